// Round 4
// baseline (240.389 us; speedup 1.0000x reference)
//
#include <hip/hip_runtime.h>
#include <math.h>

#define Bc 2
#define Vc 5
#define Cc 32
#define Dc 32
#define Hc 128
#define Wc 160
#define HWc (Hc*Wc)
#define NSLOT 48

// ---- workspace layout (in floats; _I suffixes are int-indexed via (int*)ws) ----
#define WS_RT     0                       // 8 * 12 floats (rot 9 + trans 3)
#define WS_KW     96                      // 27 collapsed conv taps
#define FLAG_I    128                     // int[2]: [128] translation-ok, [129] dvals-uniform
#define NS_I      136                     // int[8]: slots used per (b,v)
#define SHIFT_I   144                     // 8 * NSLOT * 2 ints (dx,dy)
#define WS_TAPID  912                     // 8 bv * 32 d * 8 (4 int ids, wx, wy, pad2)
#define WS_M      3584                    // fast: 8 * NSLOT * HW maps | fallback: FEATT overlay | later: PRE overlay
#define WS_FEATT  WS_M
#define WS_PRE    WS_M
#define WS_SIM    (WS_M + 8*NSLOT*HWc)    // B * D * HW, d-major

// ---- output layout (in floats) ----
#define OUT_DEPTH 0
#define OUT_CONF  (Bc*HWc)
#define OUT_PROB  (2*Bc*HWc)
#define OUT_VW    (2*Bc*HWc + Bc*Dc*HWc)

// k0: matrices, translation check, shift/tap tables, collapsed conv kernel
__global__ void prep_kernel(const float* __restrict__ pm, const float* __restrict__ reg_w,
                            const float* __restrict__ dvals, float* __restrict__ ws) {
    __shared__ int okS[8];
    int* wsi = (int*)ws;
    int t = threadIdx.x;
    if (t < Bc * (Vc - 1)) {
        int b = t / (Vc - 1);
        int v = t % (Vc - 1) + 1;
        float Pv[16], P0[16];
        for (int which = 0; which < 2; ++which) {
            int vv = which ? 0 : v;
            const float* E = pm + ((b * Vc + vv) * 2 + 0) * 16;
            const float* K = pm + ((b * Vc + vv) * 2 + 1) * 16;
            float* P = which ? P0 : Pv;
            for (int i = 0; i < 3; ++i)
                for (int j = 0; j < 4; ++j) {
                    float s = 0.f;
                    for (int k = 0; k < 3; ++k) s += K[i*4+k] * E[k*4+j];
                    P[i*4+j] = s;
                }
            for (int j = 0; j < 4; ++j) P[12+j] = E[12+j];
        }
        float A[16], I[16];
        for (int i = 0; i < 16; ++i) { A[i] = P0[i]; I[i] = (i % 5 == 0) ? 1.f : 0.f; }
        for (int col = 0; col < 4; ++col) {
            int piv = col; float best = fabsf(A[col*4+col]);
            for (int r = col+1; r < 4; ++r) { float av = fabsf(A[r*4+col]); if (av > best) { best = av; piv = r; } }
            if (piv != col)
                for (int j = 0; j < 4; ++j) {
                    float tmp = A[col*4+j]; A[col*4+j] = A[piv*4+j]; A[piv*4+j] = tmp;
                    tmp = I[col*4+j]; I[col*4+j] = I[piv*4+j]; I[piv*4+j] = tmp;
                }
            float inv = 1.f / A[col*4+col];
            for (int j = 0; j < 4; ++j) { A[col*4+j] *= inv; I[col*4+j] *= inv; }
            for (int r = 0; r < 4; ++r) if (r != col) {
                float f = A[r*4+col];
                for (int j = 0; j < 4; ++j) { A[r*4+j] -= f * A[col*4+j]; I[r*4+j] -= f * I[col*4+j]; }
            }
        }
        float M[16];
        for (int i = 0; i < 4; ++i)
            for (int j = 0; j < 4; ++j) {
                float s = 0.f;
                for (int k = 0; k < 4; ++k) s += Pv[i*4+k] * I[k*4+j];
                M[i*4+j] = s;
            }
        float* rt = ws + WS_RT + t * 12;
        for (int i = 0; i < 3; ++i)
            for (int j = 0; j < 3; ++j) rt[i*3+j] = M[i*4+j];
        rt[9] = M[3]; rt[10] = M[7]; rt[11] = M[11];

        // translation-form check
        float t0 = M[3], t1 = M[7], t2 = M[11];
        bool ok = fabsf(M[0]-1.f) < 3e-5f && fabsf(M[1]) < 3e-5f && fabsf(M[2]) < 3e-5f &&
                  fabsf(M[4]) < 3e-5f && fabsf(M[5]-1.f) < 3e-5f && fabsf(M[6]) < 3e-5f &&
                  fabsf(M[8]) < 1e-6f && fabsf(M[9]) < 1e-6f && fabsf(M[10]-1.f) < 1e-6f &&
                  fabsf(t2) < 1e-6f;
        if (ok) {
            int n = 0;
            int pid0 = 0, pid1 = 0, pid2 = 0, pid3 = 0, pix = 0, piy = 0;
            for (int d = 0; d < Dc; ++d) {
                float dv = dvals[(size_t)(b * Dc + d) * HWc];
                float sx = t0 / dv, sy = t1 / dv;
                float fx0 = floorf(sx), fy0 = floorf(sy);
                int ix = (int)fx0, iy = (int)fy0;
                float wx = sx - fx0, wy = sy - fy0;
                int dxi = ix - pix, dyi = iy - piy;
                bool reuse = (d > 0) && dxi >= -1 && dxi <= 1 && dyi >= -1 && dyi <= 1;
                int id0, id1, id2, id3;
                #define GETPREV(tx2, ty2) ((ty2)==0 ? ((tx2)==0 ? pid0 : pid1) : ((tx2)==0 ? pid2 : pid3))
                #define DOTAP(idv, tx, ty) { \
                    int tx2 = (tx) + dxi, ty2 = (ty) + dyi; \
                    if (reuse && tx2 >= 0 && tx2 <= 1 && ty2 >= 0 && ty2 <= 1) idv = GETPREV(tx2, ty2); \
                    else { if (n < NSLOT) { wsi[SHIFT_I + (t*NSLOT + n)*2] = ix + (tx); \
                                            wsi[SHIFT_I + (t*NSLOT + n)*2 + 1] = iy + (ty); } \
                           idv = n++; } }
                DOTAP(id0, 0, 0)
                DOTAP(id1, 1, 0)
                DOTAP(id2, 0, 1)
                DOTAP(id3, 1, 1)
                #undef DOTAP
                #undef GETPREV
                int base = WS_TAPID + (t * Dc + d) * 8;
                wsi[base+0] = id0; wsi[base+1] = id1; wsi[base+2] = id2; wsi[base+3] = id3;
                ws[base+4] = wx; ws[base+5] = wy; ws[base+6] = 0.f; ws[base+7] = 0.f;
                pid0 = id0; pid1 = id1; pid2 = id2; pid3 = id3; pix = ix; piy = iy;
            }
            if (n > NSLOT) ok = false;
            wsi[NS_I + t] = (n > NSLOT) ? 0 : n;
        } else {
            wsi[NS_I + t] = 0;
        }
        okS[t] = ok ? 1 : 0;
    }
    if (t >= 32 && t < 32 + 27) {
        int k = t - 32;
        float s = 0.f;
        for (int c = 0; c < Cc; ++c) s += reg_w[c * 27 + k];
        ws[WS_KW + k] = s;
    }
    __syncthreads();
    if (t == 0) {
        int f = 1;
        for (int i = 0; i < 8; ++i) f &= okS[i];
        wsi[FLAG_I] = f;
        wsi[FLAG_I + 1] = 1;
    }
}

// k0b: verify depth_values uniform over (h,w); clear flag on mismatch
__global__ void check_unif_kernel(const float* __restrict__ dvals, float* __restrict__ ws) {
    int idx = blockIdx.x * 256 + threadIdx.x;   // < B*D*HW
    int plane = idx / HWc;
    float v = dvals[idx];
    if (v != dvals[(size_t)plane * HWc]) ((int*)ws)[FLAG_I + 1] = 0;
}

// ---------- FAST PATH ----------
// kA: slot maps. thread = pixel; ref[32] in regs; s-outer, c-inner with scalar acc.
// M[bv,s,p] = valid * (1/32) * sum_c ref[c,p] * src[c, p+shift_s]
__global__ __launch_bounds__(256) void mapA_kernel(const float* __restrict__ feat,
                                                   float* __restrict__ ws) {
    const int* wsi = (const int*)ws;
    if (!(wsi[FLAG_I] & wsi[FLAG_I + 1])) return;
    __shared__ int shiftS[NSLOT * 2];
    int bv = blockIdx.y;                 // b*4 + (v-1)
    int ns = wsi[NS_I + bv];
    int b = bv >> 2, vm1 = bv & 3;
    int tid = threadIdx.x;
    if (tid < NSLOT * 2) shiftS[tid] = wsi[SHIFT_I + bv * NSLOT * 2 + tid];
    __syncthreads();

    int p = blockIdx.x * 256 + tid;
    int h = p / Wc, w = p % Wc;

    const float* refp = feat + (size_t)b * Cc * HWc + p;
    const float* srcp = feat + (size_t)((vm1 + 1) * Bc + b) * Cc * HWc;
    float rf[Cc];
    #pragma unroll
    for (int c = 0; c < Cc; ++c) rf[c] = refp[(size_t)c * HWc];

    float* Mout = ws + WS_M + (size_t)bv * NSLOT * HWc + p;
    for (int s = 0; s < ns; ++s) {
        int dx = shiftS[2 * s], dy = shiftS[2 * s + 1];
        int sw = w + dx, sh = h + dy;
        float val = 0.f;
        if (((unsigned)sw < (unsigned)Wc) && ((unsigned)sh < (unsigned)Hc)) {
            const float* sq = srcp + (sh * Wc + sw);
            float a0 = 0.f, a1 = 0.f, a2 = 0.f, a3 = 0.f;
            #pragma unroll
            for (int c = 0; c < Cc; c += 4) {
                a0 += rf[c]     * sq[(size_t)(c)     * HWc];
                a1 += rf[c + 1] * sq[(size_t)(c + 1) * HWc];
                a2 += rf[c + 2] * sq[(size_t)(c + 2) * HWc];
                a3 += rf[c + 3] * sq[(size_t)(c + 3) * HWc];
            }
            val = ((a0 + a1) + (a2 + a3)) * (1.f / 32.f);
        }
        Mout[(size_t)s * HWc] = val;
    }
}

// kB: block = 64 px x 32 d (4 waves, wave = d-octet). Fully coalesced gathers,
// scalar MLP in dl-pairs, LDS cross-wave max for view weights.
__global__ __launch_bounds__(256) void combineB_kernel(
        const float* __restrict__ w0, const float* __restrict__ b0,
        const float* __restrict__ w1, const float* __restrict__ b1,
        const float* __restrict__ w2, const float* __restrict__ b2,
        float* __restrict__ ws, float* __restrict__ out) {
    const int* wsi = (const int*)ws;
    if (!(wsi[FLAG_I] & wsi[FLAG_I + 1])) return;
    __shared__ float mlpS[180];
    __shared__ float tapS[4 * Dc * 8];      // this block's b: [4 v][32 d][8]
    __shared__ float redS[4][4][64];        // [wave][view][px]

    int tid = threadIdx.x;
    int wvid = tid >> 6;                    // d-octet 0..3
    int lane = tid & 63;
    int pg = blockIdx.x * 64 + lane;
    int b = pg / HWc, p = pg % HWc;

    if (tid < 16) mlpS[tid] = w0[tid];
    else if (tid < 32) mlpS[tid] = b0[tid - 16];
    else if (tid < 160) mlpS[tid] = w1[tid - 32];
    else if (tid < 168) mlpS[tid] = b1[tid - 160];
    else if (tid < 176) mlpS[tid] = w2[tid - 168];
    else if (tid == 176) mlpS[176] = b2[0];
    #pragma unroll
    for (int k = 0; k < 4; ++k)
        tapS[tid + k * 256] = ws[WS_TAPID + b * (4 * Dc * 8) + tid + k * 256];
    __syncthreads();

    float wvol[4][8];
    #pragma unroll
    for (int v = 0; v < 4; ++v) {
        const float* Mb = ws + WS_M + ((size_t)(b * 4 + v)) * NSLOT * HWc + p;
        float wv8[8];
        #pragma unroll
        for (int dl = 0; dl < 8; ++dl) {
            const float* rec = tapS + ((v * Dc + wvid * 8 + dl) << 3);
            float4 r0 = *(const float4*)rec;
            float4 r1 = *(const float4*)(rec + 4);
            int i00 = __float_as_int(r0.x);
            int i10 = __float_as_int(r0.y);
            int i01 = __float_as_int(r0.z);
            int i11 = __float_as_int(r0.w);
            float wx = r1.x, wy = r1.y;
            float m00 = Mb[(size_t)i00 * HWc];
            float m10 = Mb[(size_t)i10 * HWc];
            float m01 = Mb[(size_t)i01 * HWc];
            float m11 = Mb[(size_t)i11 * HWc];
            float top = m00 + wx * (m10 - m00);
            float bot = m01 + wx * (m11 - m01);
            float val = top + wy * (bot - top);
            wv8[dl] = val;
            wvol[v][dl] = val;
        }
        // MLP 1->16->8->1 on dl-pairs (shares w1 LDS reads across the pair)
        float vm = 0.f;
        #pragma unroll
        for (int pr = 0; pr < 4; ++pr) {
            float sa = wv8[2 * pr], sb = wv8[2 * pr + 1];
            float ha[16], hb[16];
            #pragma unroll
            for (int i = 0; i < 16; ++i) {
                float wi = mlpS[i], bi = mlpS[16 + i];
                ha[i] = fmaxf(wi * sa + bi, 0.f);
                hb[i] = fmaxf(wi * sb + bi, 0.f);
            }
            float bias2 = mlpS[176];
            float ya = bias2, yb = bias2;
            #pragma unroll
            for (int j = 0; j < 8; ++j) {
                float a0 = mlpS[160 + j];
                float aa = a0, ab = a0;
                #pragma unroll
                for (int k = 0; k < 4; ++k) {
                    float4 wq = *(const float4*)(mlpS + 32 + j * 16 + k * 4);
                    aa += wq.x * ha[4*k] + wq.y * ha[4*k+1] + wq.z * ha[4*k+2] + wq.w * ha[4*k+3];
                    ab += wq.x * hb[4*k] + wq.y * hb[4*k+1] + wq.z * hb[4*k+2] + wq.w * hb[4*k+3];
                }
                float w2j = mlpS[168 + j];
                ya += w2j * fmaxf(aa, 0.f);
                yb += w2j * fmaxf(ab, 0.f);
            }
            float siga = __fdividef(1.f, 1.f + __expf(-ya));
            float sigb = __fdividef(1.f, 1.f + __expf(-yb));
            vm = fmaxf(vm, fmaxf(siga, sigb));
        }
        redS[wvid][v][lane] = vm;
    }
    __syncthreads();

    float vw[4];
    float wsum = 1e-5f;
    #pragma unroll
    for (int v = 0; v < 4; ++v) {
        float m = fmaxf(fmaxf(redS[0][v][lane], redS[1][v][lane]),
                        fmaxf(redS[2][v][lane], redS[3][v][lane]));
        vw[v] = m;
        wsum += m;
    }
    float invw = __fdividef(1.f, wsum);
    #pragma unroll
    for (int dl = 0; dl < 8; ++dl) {
        float vol = wvol[0][dl] * vw[0] + wvol[1][dl] * vw[1]
                  + wvol[2][dl] * vw[2] + wvol[3][dl] * vw[3];
        ws[WS_SIM + ((size_t)(b * Dc + wvid * 8 + dl)) * HWc + p] = vol * invw;
    }
    if (wvid == 0) {
        #pragma unroll
        for (int v = 0; v < 4; ++v)
            out[OUT_VW + ((size_t)(b * 4 + v)) * HWc + p] = vw[v];
    }
}

// ---------- FALLBACK PATH (generic; gated off when fast path valid) ----------
__global__ void transpose_kernel(const float* __restrict__ feat, float* __restrict__ ws) {
    const int* wsi = (const int*)ws;
    if (wsi[FLAG_I] & wsi[FLAG_I + 1]) return;
    __shared__ float tile[32][33];
    int slab = blockIdx.x;          // 0..9 (V*B)
    int pbase = blockIdx.y * 32;
    int tid = threadIdx.x;
    const float* src = feat + (size_t)slab * Cc * HWc;
    float* dst = ws + WS_FEATT + (size_t)slab * HWc * Cc;
    int cc = tid >> 5, pp = tid & 31;
    #pragma unroll
    for (int i = 0; i < 4; ++i) {
        int c = cc + 8 * i;
        tile[c][pp] = src[(size_t)c * HWc + pbase + pp];
    }
    __syncthreads();
    int c2 = tid & 31, p2 = tid >> 5;
    #pragma unroll
    for (int i = 0; i < 4; ++i) {
        int pq = p2 + 8 * i;
        dst[((size_t)(pbase + pq)) * 32 + c2] = tile[c2][pq];
    }
}

__global__ __launch_bounds__(256) void fb_main_kernel(
        const float* __restrict__ dvals,
        const float* __restrict__ w0, const float* __restrict__ b0,
        const float* __restrict__ w1, const float* __restrict__ b1,
        const float* __restrict__ w2, const float* __restrict__ b2,
        float* __restrict__ ws, float* __restrict__ out) {
    const int* wsi = (const int*)ws;
    if (wsi[FLAG_I] & wsi[FLAG_I + 1]) return;
    __shared__ float mlpS[177];
    __shared__ float rtS[48];

    int bid = blockIdx.x;
    int b = bid / (HWc / 8);
    int pblk = (bid % (HWc / 8)) * 8;
    int tid = threadIdx.x;
    int d = tid & 31;
    int pg = tid >> 5;
    int p = pblk + pg;
    int h = p / Wc, w = p % Wc;

    if (tid < 16) mlpS[tid] = w0[tid];
    else if (tid < 32) mlpS[tid] = b0[tid - 16];
    else if (tid < 160) mlpS[tid] = w1[tid - 32];
    else if (tid < 168) mlpS[tid] = b1[tid - 160];
    else if (tid < 176) mlpS[tid] = w2[tid - 168];
    else if (tid == 176) mlpS[176] = b2[0];
    if (tid >= 192 && tid < 240) rtS[tid - 192] = ws[WS_RT + b * 48 + (tid - 192)];
    __syncthreads();

    const float4* refp = (const float4*)(ws + WS_FEATT + ((size_t)b * HWc + p) * Cc);
    float4 rf[8];
    #pragma unroll
    for (int i = 0; i < 8; ++i) rf[i] = refp[i];

    float depth = dvals[((size_t)(b * Dc + d)) * HWc + p];
    float fx = (float)w, fy = (float)h;

    float sv[4];
    #pragma unroll
    for (int v = 0; v < 4; ++v) {
        const float* rt = rtS + v * 12;
        float px = (rt[0] * fx + rt[1] * fy + rt[2]) * depth + rt[9];
        float py = (rt[3] * fx + rt[4] * fy + rt[5]) * depth + rt[10];
        float pz = (rt[6] * fx + rt[7] * fy + rt[8]) * depth + rt[11];
        float xs = __fdividef(px, pz);
        float ys = __fdividef(py, pz);
        float fx0 = floorf(xs), fy0 = floorf(ys);
        float wx = xs - fx0, wy = ys - fy0;

        const float* featv = ws + WS_FEATT + ((size_t)((v + 1) * Bc + b)) * HWc * Cc;
        float acc = 0.f;
        #pragma unroll
        for (int ty = 0; ty < 2; ++ty) {
            #pragma unroll
            for (int tx = 0; tx < 2; ++tx) {
                float fxt = fx0 + (float)tx;
                float fyt = fy0 + (float)ty;
                bool valid = (fxt >= 0.f) && (fxt <= (float)(Wc - 1)) &&
                             (fyt >= 0.f) && (fyt <= (float)(Hc - 1));
                float wt = (tx ? wx : 1.f - wx) * (ty ? wy : 1.f - wy);
                if (valid) {
                    int ix = (int)fxt, iy = (int)fyt;
                    const float4* fp = (const float4*)(featv + ((size_t)iy * Wc + ix) * Cc);
                    float dot = 0.f;
                    #pragma unroll
                    for (int i = 0; i < 8; ++i) {
                        float4 fv = fp[i];
                        dot += fv.x * rf[i].x + fv.y * rf[i].y + fv.z * rf[i].z + fv.w * rf[i].w;
                    }
                    acc += wt * dot;
                }
            }
        }
        sv[v] = acc * (1.f / (float)Cc);
    }

    float h1[16][4];
    #pragma unroll
    for (int i = 0; i < 16; ++i) {
        float a = mlpS[i], bb = mlpS[16 + i];
        #pragma unroll
        for (int v = 0; v < 4; ++v) h1[i][v] = fmaxf(a * sv[v] + bb, 0.f);
    }
    float bias2 = mlpS[176];
    float y[4] = {bias2, bias2, bias2, bias2};
    const float4* w1v = (const float4*)(mlpS + 32);
    #pragma unroll
    for (int j = 0; j < 8; ++j) {
        float a0 = mlpS[160 + j];
        float acc[4] = {a0, a0, a0, a0};
        #pragma unroll
        for (int k = 0; k < 4; ++k) {
            float4 wq = w1v[j * 4 + k];
            #pragma unroll
            for (int v = 0; v < 4; ++v) {
                acc[v] += wq.x * h1[4*k+0][v] + wq.y * h1[4*k+1][v]
                        + wq.z * h1[4*k+2][v] + wq.w * h1[4*k+3][v];
            }
        }
        float w2j = mlpS[168 + j];
        #pragma unroll
        for (int v = 0; v < 4; ++v) y[v] += w2j * fmaxf(acc[v], 0.f);
    }

    float vw[4];
    #pragma unroll
    for (int v = 0; v < 4; ++v) {
        float m = __fdividef(1.f, 1.f + __expf(-y[v]));
        #pragma unroll
        for (int off = 16; off; off >>= 1) m = fmaxf(m, __shfl_xor(m, off));
        vw[v] = m;
    }

    float wsum = 1e-5f + vw[0] + vw[1] + vw[2] + vw[3];
    float vol = sv[0] * vw[0] + sv[1] * vw[1] + sv[2] * vw[2] + sv[3] * vw[3];
    ws[WS_SIM + ((size_t)(b * Dc + d)) * HWc + p] = __fdividef(vol, wsum);

    if (d < 4)
        out[OUT_VW + ((size_t)b * 4 + d) * HWc + p] = vw[d];
}

// ---------- SHARED TAIL ----------
__global__ __launch_bounds__(256) void conv_kernel(const float* __restrict__ regb,
                                                   float* __restrict__ ws) {
    int p = blockIdx.x * 256 + threadIdx.x;
    int b = blockIdx.y;
    int q = blockIdx.z;          // d-quad: outputs d = 4q..4q+3
    int h = p / Wc, w = p % Wc;

    float kw[27];
    #pragma unroll
    for (int i = 0; i < 27; ++i) kw[i] = ws[WS_KW + i];

    const float* simb = ws + WS_SIM + (size_t)b * Dc * HWc;
    float acc[4] = {0.f, 0.f, 0.f, 0.f};
    #pragma unroll
    for (int e = -1; e <= 4; ++e) {
        int dd = q * 4 + e;
        if (dd < 0 || dd >= Dc) continue;
        float val[3][3];
        #pragma unroll
        for (int i = 0; i < 3; ++i) {
            int hh = h + i - 1;
            #pragma unroll
            for (int j = 0; j < 3; ++j) {
                int wwp = w + j - 1;
                bool ok = ((unsigned)hh < (unsigned)Hc) && ((unsigned)wwp < (unsigned)Wc);
                val[i][j] = ok ? simb[(size_t)dd * HWc + hh * Wc + wwp] : 0.f;
            }
        }
        #pragma unroll
        for (int kd = 0; kd < 3; ++kd) {
            int tgt = e - kd + 1;
            if (tgt < 0 || tgt > 3) continue;
            float hs = 0.f;
            #pragma unroll
            for (int i = 0; i < 3; ++i)
                #pragma unroll
                for (int j = 0; j < 3; ++j)
                    hs += kw[kd * 9 + i * 3 + j] * val[i][j];
            acc[tgt] += hs;
        }
    }
    float bb = regb[0];
    #pragma unroll
    for (int r = 0; r < 4; ++r)
        ws[WS_PRE + ((size_t)(b * Dc + q * 4 + r)) * HWc + p] = acc[r] + bb;
}

__global__ __launch_bounds__(256) void softmax_kernel(const float* __restrict__ dvals,
                                                      const float* __restrict__ ws,
                                                      float* __restrict__ out) {
    int idx = blockIdx.x * 256 + threadIdx.x;   // B*HW*4
    int lane = idx & 63;
    int t = lane >> 4;
    int pw = lane & 15;
    int P = (idx >> 6) * 16 + pw;
    int b = P / HWc, p = P % HWc;

    const float* preb = ws + WS_PRE + (size_t)b * Dc * HWc + p;
    float pr[8];
    #pragma unroll
    for (int k = 0; k < 8; ++k) pr[k] = preb[(size_t)(t * 8 + k) * HWc];

    float m = pr[0]; int am = t * 8;
    #pragma unroll
    for (int k = 1; k < 8; ++k) if (pr[k] > m) { m = pr[k]; am = t * 8 + k; }
    #pragma unroll
    for (int s = 16; s <= 32; s <<= 1) {
        float om = __shfl_xor(m, s);
        int oi = __shfl_xor(am, s);
        if (om > m || (om == m && oi < am)) { m = om; am = oi; }
    }
    float e[8]; float sum = 0.f;
    #pragma unroll
    for (int k = 0; k < 8; ++k) { e[k] = __expf(pr[k] - m); sum += e[k]; }
    #pragma unroll
    for (int s = 16; s <= 32; s <<= 1) sum += __shfl_xor(sum, s);
    float inv = __fdividef(1.f, sum);
    #pragma unroll
    for (int k = 0; k < 8; ++k)
        out[OUT_PROB + ((size_t)(b * Dc + t * 8 + k)) * HWc + p] = e[k] * inv;
    if (t == 0) {
        out[OUT_DEPTH + (size_t)b * HWc + p] = dvals[((size_t)(b * Dc + am)) * HWc + p];
        out[OUT_CONF + (size_t)b * HWc + p] = inv;
    }
}

extern "C" void kernel_launch(void* const* d_in, const int* in_sizes, int n_in,
                              void* d_out, int out_size, void* d_ws, size_t ws_size,
                              hipStream_t stream) {
    const float* features = (const float*)d_in[0];   // (V,B,C,H,W)
    const float* pm       = (const float*)d_in[1];   // (B,V,2,4,4)
    const float* dvals    = (const float*)d_in[2];   // (B,D,H,W)
    const float* pw_w0    = (const float*)d_in[3];
    const float* pw_b0    = (const float*)d_in[4];
    const float* pw_w1    = (const float*)d_in[5];
    const float* pw_b1    = (const float*)d_in[6];
    const float* pw_w2    = (const float*)d_in[7];
    const float* pw_b2    = (const float*)d_in[8];
    const float* reg_w    = (const float*)d_in[9];
    const float* reg_b    = (const float*)d_in[10];
    float* out = (float*)d_out;
    float* ws  = (float*)d_ws;

    prep_kernel<<<1, 64, 0, stream>>>(pm, reg_w, dvals, ws);
    check_unif_kernel<<<(Bc * Dc * HWc) / 256, 256, 0, stream>>>(dvals, ws);
    // fallback path (early-exits when fast path valid)
    transpose_kernel<<<dim3(Vc * Bc, HWc / 32), 256, 0, stream>>>(features, ws);
    // fast path
    mapA_kernel<<<dim3(HWc / 256, 8), 256, 0, stream>>>(features, ws);
    fb_main_kernel<<<Bc * HWc / 8, 256, 0, stream>>>(dvals, pw_w0, pw_b0, pw_w1, pw_b1,
                                                     pw_w2, pw_b2, ws, out);
    combineB_kernel<<<Bc * HWc / 64, 256, 0, stream>>>(pw_w0, pw_b0, pw_w1, pw_b1,
                                                       pw_w2, pw_b2, ws, out);
    // shared tail
    conv_kernel<<<dim3(HWc / 256, Bc, 8), 256, 0, stream>>>(reg_b, ws);
    softmax_kernel<<<(Bc * HWc * 4) / 256, 256, 0, stream>>>(dvals, ws, out);
}

// Round 5
// 142.602 us; speedup vs baseline: 1.6857x; 1.6857x over previous
//
#include <hip/hip_runtime.h>
#include <math.h>

#define Bc 2
#define Vc 5
#define Cc 32
#define Dc 32
#define Hc 128
#define Wc 160
#define HWc (Hc*Wc)
#define NSLOT 44

// ---- workspace layout (in floats; _I suffixes are int-indexed via (int*)ws) ----
#define WS_RT     0                       // 8 * 12 floats (rot 9 + trans 3)
#define WS_KW     96                      // 27 collapsed conv taps
#define FLAG_I    128                     // int[2]: [128] translation-ok, [129] dvals-uniform
#define NS_I      136                     // int[8]: slots used per (b,v)
#define SHIFT_I   144                     // 8 * NSLOT * 2 ints (dx,dy)
#define WS_TAPID  912                     // 8 bv * 32 d * 8 (4 int ids, wx, wy, pad2)
#define WS_M      3584                    // fast: 8 * NSLOT * HW maps | fallback: FEATT overlay | later: PRE overlay
#define WS_FEATT  WS_M
#define WS_PRE    WS_M
#define WS_SIM    (WS_M + 8*NSLOT*HWc)    // B * D * HW, d-major
#define WS_VWP    (WS_SIM + Bc*Dc*HWc)    // B * 4v * 4oct * HW partial view-weight maxes
// end = WS_VWP + Bc*4*4*HWc = 9,178,624 floats (~36.7 MB, same as prior rounds)

// ---- output layout (in floats) ----
#define OUT_DEPTH 0
#define OUT_CONF  (Bc*HWc)
#define OUT_PROB  (2*Bc*HWc)
#define OUT_VW    (2*Bc*HWc + Bc*Dc*HWc)

// k0: matrices, translation check, shift/tap tables, collapsed conv kernel
__global__ void prep_kernel(const float* __restrict__ pm, const float* __restrict__ reg_w,
                            const float* __restrict__ dvals, float* __restrict__ ws) {
    __shared__ int okS[8];
    int* wsi = (int*)ws;
    int t = threadIdx.x;
    if (t < Bc * (Vc - 1)) {
        int b = t / (Vc - 1);
        int v = t % (Vc - 1) + 1;
        float Pv[16], P0[16];
        for (int which = 0; which < 2; ++which) {
            int vv = which ? 0 : v;
            const float* E = pm + ((b * Vc + vv) * 2 + 0) * 16;
            const float* K = pm + ((b * Vc + vv) * 2 + 1) * 16;
            float* P = which ? P0 : Pv;
            for (int i = 0; i < 3; ++i)
                for (int j = 0; j < 4; ++j) {
                    float s = 0.f;
                    for (int k = 0; k < 3; ++k) s += K[i*4+k] * E[k*4+j];
                    P[i*4+j] = s;
                }
            for (int j = 0; j < 4; ++j) P[12+j] = E[12+j];
        }
        float A[16], I[16];
        for (int i = 0; i < 16; ++i) { A[i] = P0[i]; I[i] = (i % 5 == 0) ? 1.f : 0.f; }
        for (int col = 0; col < 4; ++col) {
            int piv = col; float best = fabsf(A[col*4+col]);
            for (int r = col+1; r < 4; ++r) { float av = fabsf(A[r*4+col]); if (av > best) { best = av; piv = r; } }
            if (piv != col)
                for (int j = 0; j < 4; ++j) {
                    float tmp = A[col*4+j]; A[col*4+j] = A[piv*4+j]; A[piv*4+j] = tmp;
                    tmp = I[col*4+j]; I[col*4+j] = I[piv*4+j]; I[piv*4+j] = tmp;
                }
            float inv = 1.f / A[col*4+col];
            for (int j = 0; j < 4; ++j) { A[col*4+j] *= inv; I[col*4+j] *= inv; }
            for (int r = 0; r < 4; ++r) if (r != col) {
                float f = A[r*4+col];
                for (int j = 0; j < 4; ++j) { A[r*4+j] -= f * A[col*4+j]; I[r*4+j] -= f * I[col*4+j]; }
            }
        }
        float M[16];
        for (int i = 0; i < 4; ++i)
            for (int j = 0; j < 4; ++j) {
                float s = 0.f;
                for (int k = 0; k < 4; ++k) s += Pv[i*4+k] * I[k*4+j];
                M[i*4+j] = s;
            }
        float* rt = ws + WS_RT + t * 12;
        for (int i = 0; i < 3; ++i)
            for (int j = 0; j < 3; ++j) rt[i*3+j] = M[i*4+j];
        rt[9] = M[3]; rt[10] = M[7]; rt[11] = M[11];

        // translation-form check
        float t0 = M[3], t1 = M[7], t2 = M[11];
        bool ok = fabsf(M[0]-1.f) < 3e-5f && fabsf(M[1]) < 3e-5f && fabsf(M[2]) < 3e-5f &&
                  fabsf(M[4]) < 3e-5f && fabsf(M[5]-1.f) < 3e-5f && fabsf(M[6]) < 3e-5f &&
                  fabsf(M[8]) < 1e-6f && fabsf(M[9]) < 1e-6f && fabsf(M[10]-1.f) < 1e-6f &&
                  fabsf(t2) < 1e-6f;
        if (ok) {
            int n = 0;
            int pid0 = 0, pid1 = 0, pid2 = 0, pid3 = 0, pix = 0, piy = 0;
            for (int d = 0; d < Dc; ++d) {
                float dv = dvals[(size_t)(b * Dc + d) * HWc];
                float sx = t0 / dv, sy = t1 / dv;
                float fx0 = floorf(sx), fy0 = floorf(sy);
                int ix = (int)fx0, iy = (int)fy0;
                float wx = sx - fx0, wy = sy - fy0;
                int dxi = ix - pix, dyi = iy - piy;
                bool reuse = (d > 0) && dxi >= -1 && dxi <= 1 && dyi >= -1 && dyi <= 1;
                int id0, id1, id2, id3;
                #define GETPREV(tx2, ty2) ((ty2)==0 ? ((tx2)==0 ? pid0 : pid1) : ((tx2)==0 ? pid2 : pid3))
                #define DOTAP(idv, tx, ty) { \
                    int tx2 = (tx) + dxi, ty2 = (ty) + dyi; \
                    if (reuse && tx2 >= 0 && tx2 <= 1 && ty2 >= 0 && ty2 <= 1) idv = GETPREV(tx2, ty2); \
                    else { if (n < NSLOT) { wsi[SHIFT_I + (t*NSLOT + n)*2] = ix + (tx); \
                                            wsi[SHIFT_I + (t*NSLOT + n)*2 + 1] = iy + (ty); } \
                           idv = n++; } }
                DOTAP(id0, 0, 0)
                DOTAP(id1, 1, 0)
                DOTAP(id2, 0, 1)
                DOTAP(id3, 1, 1)
                #undef DOTAP
                #undef GETPREV
                int base = WS_TAPID + (t * Dc + d) * 8;
                wsi[base+0] = id0; wsi[base+1] = id1; wsi[base+2] = id2; wsi[base+3] = id3;
                ws[base+4] = wx; ws[base+5] = wy; ws[base+6] = 0.f; ws[base+7] = 0.f;
                pid0 = id0; pid1 = id1; pid2 = id2; pid3 = id3; pix = ix; piy = iy;
            }
            if (n > NSLOT) ok = false;
            wsi[NS_I + t] = (n > NSLOT) ? 0 : n;
        } else {
            wsi[NS_I + t] = 0;
        }
        okS[t] = ok ? 1 : 0;
    }
    if (t >= 32 && t < 32 + 27) {
        int k = t - 32;
        float s = 0.f;
        for (int c = 0; c < Cc; ++c) s += reg_w[c * 27 + k];
        ws[WS_KW + k] = s;
    }
    __syncthreads();
    if (t == 0) {
        int f = 1;
        for (int i = 0; i < 8; ++i) f &= okS[i];
        wsi[FLAG_I] = f;
        wsi[FLAG_I + 1] = 1;
    }
}

// k0b: verify depth_values uniform over (h,w); clear flag on mismatch
__global__ void check_unif_kernel(const float* __restrict__ dvals, float* __restrict__ ws) {
    int idx = blockIdx.x * 256 + threadIdx.x;   // < B*D*HW
    int plane = idx / HWc;
    float v = dvals[idx];
    if (v != dvals[(size_t)plane * HWc]) ((int*)ws)[FLAG_I + 1] = 0;
}

// ---------- FAST PATH ----------
// kA: slot maps. thread = pixel; ref[32] in regs; s-outer, c-inner with scalar acc.
__global__ __launch_bounds__(256) void mapA_kernel(const float* __restrict__ feat,
                                                   float* __restrict__ ws) {
    const int* wsi = (const int*)ws;
    if (!(wsi[FLAG_I] & wsi[FLAG_I + 1])) return;
    __shared__ int shiftS[NSLOT * 2];
    int bv = blockIdx.y;                 // b*4 + (v-1)
    int ns = wsi[NS_I + bv];
    int b = bv >> 2, vm1 = bv & 3;
    int tid = threadIdx.x;
    if (tid < NSLOT * 2) shiftS[tid] = wsi[SHIFT_I + bv * NSLOT * 2 + tid];
    __syncthreads();

    int p = blockIdx.x * 256 + tid;
    int h = p / Wc, w = p % Wc;

    const float* refp = feat + (size_t)b * Cc * HWc + p;
    const float* srcp = feat + (size_t)((vm1 + 1) * Bc + b) * Cc * HWc;
    float rf[Cc];
    #pragma unroll
    for (int c = 0; c < Cc; ++c) rf[c] = refp[(size_t)c * HWc];

    float* Mout = ws + WS_M + (size_t)bv * NSLOT * HWc + p;
    for (int s = 0; s < ns; ++s) {
        int dx = shiftS[2 * s], dy = shiftS[2 * s + 1];
        int sw = w + dx, sh = h + dy;
        float val = 0.f;
        if (((unsigned)sw < (unsigned)Wc) && ((unsigned)sh < (unsigned)Hc)) {
            const float* sq = srcp + (sh * Wc + sw);
            float a0 = 0.f, a1 = 0.f, a2 = 0.f, a3 = 0.f;
            #pragma unroll
            for (int c = 0; c < Cc; c += 4) {
                a0 += rf[c]     * sq[(size_t)(c)     * HWc];
                a1 += rf[c + 1] * sq[(size_t)(c + 1) * HWc];
                a2 += rf[c + 2] * sq[(size_t)(c + 2) * HWc];
                a3 += rf[c + 3] * sq[(size_t)(c + 3) * HWc];
            }
            val = ((a0 + a1) + (a2 + a3)) * (1.f / 32.f);
        }
        Mout[(size_t)s * HWc] = val;
    }
}

// kB1: view-weight partials. thread = pixel; loop 8 depths (blockIdx.y octet) x 4 views;
// 4-wide MLP (R2-proven 56-VGPR structure); running max only; no retained similarities.
__global__ __launch_bounds__(256) void viewweight_kernel(
        const float* __restrict__ w0, const float* __restrict__ b0,
        const float* __restrict__ w1, const float* __restrict__ b1,
        const float* __restrict__ w2, const float* __restrict__ b2,
        float* __restrict__ ws) {
    const int* wsi = (const int*)ws;
    if (!(wsi[FLAG_I] & wsi[FLAG_I + 1])) return;
    __shared__ float mlpS[177];
    __shared__ float tapS[4 * 8 * 8];       // [4 v][8 d][8]

    int tid = threadIdx.x;
    int pg = blockIdx.x * 256 + tid;        // global pixel 0..B*HW-1
    int b = pg / HWc, p = pg % HWc;         // b uniform per block (HW % 256 == 0)
    int oct = blockIdx.y;

    if (tid < 16) mlpS[tid] = w0[tid];
    else if (tid < 32) mlpS[tid] = b0[tid - 16];
    else if (tid < 160) mlpS[tid] = w1[tid - 32];
    else if (tid < 168) mlpS[tid] = b1[tid - 160];
    else if (tid < 176) mlpS[tid] = w2[tid - 168];
    else if (tid == 176) mlpS[176] = b2[0];
    {
        int v = tid >> 6, dl = (tid >> 3) & 7, f = tid & 7;
        tapS[tid] = ws[WS_TAPID + (((b * 4 + v) * Dc) + oct * 8 + dl) * 8 + f];
    }
    __syncthreads();

    float vm[4] = {0.f, 0.f, 0.f, 0.f};
    for (int dl = 0; dl < 8; ++dl) {
        float sv[4];
        #pragma unroll
        for (int v = 0; v < 4; ++v) {
            const float* rec = tapS + ((v * 8 + dl) << 3);
            int i00 = __float_as_int(rec[0]);
            int i10 = __float_as_int(rec[1]);
            int i01 = __float_as_int(rec[2]);
            int i11 = __float_as_int(rec[3]);
            float wx = rec[4], wy = rec[5];
            const float* Mb = ws + WS_M + ((size_t)(b * 4 + v)) * NSLOT * HWc + p;
            float m00 = Mb[(size_t)i00 * HWc];
            float m10 = Mb[(size_t)i10 * HWc];
            float m01 = Mb[(size_t)i01 * HWc];
            float m11 = Mb[(size_t)i11 * HWc];
            float top = m00 + wx * (m10 - m00);
            float bot = m01 + wx * (m11 - m01);
            sv[v] = top + wy * (bot - top);
        }
        // 4-wide MLP 1->16->8->1
        float h1[16][4];
        #pragma unroll
        for (int i = 0; i < 16; ++i) {
            float a = mlpS[i], bb = mlpS[16 + i];
            #pragma unroll
            for (int v = 0; v < 4; ++v) h1[i][v] = fmaxf(a * sv[v] + bb, 0.f);
        }
        float bias2 = mlpS[176];
        float y[4] = {bias2, bias2, bias2, bias2};
        const float4* w1v = (const float4*)(mlpS + 32);
        #pragma unroll
        for (int j = 0; j < 8; ++j) {
            float a0 = mlpS[160 + j];
            float acc[4] = {a0, a0, a0, a0};
            #pragma unroll
            for (int k = 0; k < 4; ++k) {
                float4 wq = w1v[j * 4 + k];
                #pragma unroll
                for (int v = 0; v < 4; ++v) {
                    acc[v] += wq.x * h1[4*k+0][v] + wq.y * h1[4*k+1][v]
                            + wq.z * h1[4*k+2][v] + wq.w * h1[4*k+3][v];
                }
            }
            float w2j = mlpS[168 + j];
            #pragma unroll
            for (int v = 0; v < 4; ++v) y[v] += w2j * fmaxf(acc[v], 0.f);
        }
        #pragma unroll
        for (int v = 0; v < 4; ++v)
            vm[v] = fmaxf(vm[v], __fdividef(1.f, 1.f + __expf(-y[v])));
    }
    #pragma unroll
    for (int v = 0; v < 4; ++v)
        ws[WS_VWP + ((size_t)((b * 4 + v) * 4 + oct)) * HWc + p] = vm[v];
}

// kB2: similarity. thread = pixel; reduce 16 vw partials; loop 8 depths re-gathering maps.
__global__ __launch_bounds__(256) void simcombine_kernel(float* __restrict__ ws,
                                                         float* __restrict__ out) {
    const int* wsi = (const int*)ws;
    if (!(wsi[FLAG_I] & wsi[FLAG_I + 1])) return;
    __shared__ float tapS[4 * 8 * 8];

    int tid = threadIdx.x;
    int pg = blockIdx.x * 256 + tid;
    int b = pg / HWc, p = pg % HWc;
    int oct = blockIdx.y;

    {
        int v = tid >> 6, dl = (tid >> 3) & 7, f = tid & 7;
        tapS[tid] = ws[WS_TAPID + (((b * 4 + v) * Dc) + oct * 8 + dl) * 8 + f];
    }
    __syncthreads();

    float vw[4];
    float wsum = 1e-5f;
    #pragma unroll
    for (int v = 0; v < 4; ++v) {
        const float* vp = ws + WS_VWP + ((size_t)((b * 4 + v) * 4)) * HWc + p;
        float m = fmaxf(fmaxf(vp[0], vp[(size_t)HWc]),
                        fmaxf(vp[(size_t)2 * HWc], vp[(size_t)3 * HWc]));
        vw[v] = m;
        wsum += m;
    }
    float invw = __fdividef(1.f, wsum);

    for (int dl = 0; dl < 8; ++dl) {
        float vol = 0.f;
        #pragma unroll
        for (int v = 0; v < 4; ++v) {
            const float* rec = tapS + ((v * 8 + dl) << 3);
            int i00 = __float_as_int(rec[0]);
            int i10 = __float_as_int(rec[1]);
            int i01 = __float_as_int(rec[2]);
            int i11 = __float_as_int(rec[3]);
            float wx = rec[4], wy = rec[5];
            const float* Mb = ws + WS_M + ((size_t)(b * 4 + v)) * NSLOT * HWc + p;
            float m00 = Mb[(size_t)i00 * HWc];
            float m10 = Mb[(size_t)i10 * HWc];
            float m01 = Mb[(size_t)i01 * HWc];
            float m11 = Mb[(size_t)i11 * HWc];
            float top = m00 + wx * (m10 - m00);
            float bot = m01 + wx * (m11 - m01);
            vol += (top + wy * (bot - top)) * vw[v];
        }
        ws[WS_SIM + ((size_t)(b * Dc + oct * 8 + dl)) * HWc + p] = vol * invw;
    }
    if (oct == 0) {
        #pragma unroll
        for (int v = 0; v < 4; ++v)
            out[OUT_VW + ((size_t)(b * 4 + v)) * HWc + p] = vw[v];
    }
}

// ---------- FALLBACK PATH (generic; gated off when fast path valid) ----------
__global__ void transpose_kernel(const float* __restrict__ feat, float* __restrict__ ws) {
    const int* wsi = (const int*)ws;
    if (wsi[FLAG_I] & wsi[FLAG_I + 1]) return;
    __shared__ float tile[32][33];
    int slab = blockIdx.x;          // 0..9 (V*B)
    int pbase = blockIdx.y * 32;
    int tid = threadIdx.x;
    const float* src = feat + (size_t)slab * Cc * HWc;
    float* dst = ws + WS_FEATT + (size_t)slab * HWc * Cc;
    int cc = tid >> 5, pp = tid & 31;
    #pragma unroll
    for (int i = 0; i < 4; ++i) {
        int c = cc + 8 * i;
        tile[c][pp] = src[(size_t)c * HWc + pbase + pp];
    }
    __syncthreads();
    int c2 = tid & 31, p2 = tid >> 5;
    #pragma unroll
    for (int i = 0; i < 4; ++i) {
        int pq = p2 + 8 * i;
        dst[((size_t)(pbase + pq)) * 32 + c2] = tile[c2][pq];
    }
}

__global__ __launch_bounds__(256) void fb_main_kernel(
        const float* __restrict__ dvals,
        const float* __restrict__ w0, const float* __restrict__ b0,
        const float* __restrict__ w1, const float* __restrict__ b1,
        const float* __restrict__ w2, const float* __restrict__ b2,
        float* __restrict__ ws, float* __restrict__ out) {
    const int* wsi = (const int*)ws;
    if (wsi[FLAG_I] & wsi[FLAG_I + 1]) return;
    __shared__ float mlpS[177];
    __shared__ float rtS[48];

    int bid = blockIdx.x;
    int b = bid / (HWc / 8);
    int pblk = (bid % (HWc / 8)) * 8;
    int tid = threadIdx.x;
    int d = tid & 31;
    int pg = tid >> 5;
    int p = pblk + pg;
    int h = p / Wc, w = p % Wc;

    if (tid < 16) mlpS[tid] = w0[tid];
    else if (tid < 32) mlpS[tid] = b0[tid - 16];
    else if (tid < 160) mlpS[tid] = w1[tid - 32];
    else if (tid < 168) mlpS[tid] = b1[tid - 160];
    else if (tid < 176) mlpS[tid] = w2[tid - 168];
    else if (tid == 176) mlpS[176] = b2[0];
    if (tid >= 192 && tid < 240) rtS[tid - 192] = ws[WS_RT + b * 48 + (tid - 192)];
    __syncthreads();

    const float4* refp = (const float4*)(ws + WS_FEATT + ((size_t)b * HWc + p) * Cc);
    float4 rf[8];
    #pragma unroll
    for (int i = 0; i < 8; ++i) rf[i] = refp[i];

    float depth = dvals[((size_t)(b * Dc + d)) * HWc + p];
    float fx = (float)w, fy = (float)h;

    float sv[4];
    #pragma unroll
    for (int v = 0; v < 4; ++v) {
        const float* rt = rtS + v * 12;
        float px = (rt[0] * fx + rt[1] * fy + rt[2]) * depth + rt[9];
        float py = (rt[3] * fx + rt[4] * fy + rt[5]) * depth + rt[10];
        float pz = (rt[6] * fx + rt[7] * fy + rt[8]) * depth + rt[11];
        float xs = __fdividef(px, pz);
        float ys = __fdividef(py, pz);
        float fx0 = floorf(xs), fy0 = floorf(ys);
        float wx = xs - fx0, wy = ys - fy0;

        const float* featv = ws + WS_FEATT + ((size_t)((v + 1) * Bc + b)) * HWc * Cc;
        float acc = 0.f;
        #pragma unroll
        for (int ty = 0; ty < 2; ++ty) {
            #pragma unroll
            for (int tx = 0; tx < 2; ++tx) {
                float fxt = fx0 + (float)tx;
                float fyt = fy0 + (float)ty;
                bool valid = (fxt >= 0.f) && (fxt <= (float)(Wc - 1)) &&
                             (fyt >= 0.f) && (fyt <= (float)(Hc - 1));
                float wt = (tx ? wx : 1.f - wx) * (ty ? wy : 1.f - wy);
                if (valid) {
                    int ix = (int)fxt, iy = (int)fyt;
                    const float4* fp = (const float4*)(featv + ((size_t)iy * Wc + ix) * Cc);
                    float dot = 0.f;
                    #pragma unroll
                    for (int i = 0; i < 8; ++i) {
                        float4 fv = fp[i];
                        dot += fv.x * rf[i].x + fv.y * rf[i].y + fv.z * rf[i].z + fv.w * rf[i].w;
                    }
                    acc += wt * dot;
                }
            }
        }
        sv[v] = acc * (1.f / (float)Cc);
    }

    float h1[16][4];
    #pragma unroll
    for (int i = 0; i < 16; ++i) {
        float a = mlpS[i], bb = mlpS[16 + i];
        #pragma unroll
        for (int v = 0; v < 4; ++v) h1[i][v] = fmaxf(a * sv[v] + bb, 0.f);
    }
    float bias2 = mlpS[176];
    float y[4] = {bias2, bias2, bias2, bias2};
    const float4* w1v = (const float4*)(mlpS + 32);
    #pragma unroll
    for (int j = 0; j < 8; ++j) {
        float a0 = mlpS[160 + j];
        float acc[4] = {a0, a0, a0, a0};
        #pragma unroll
        for (int k = 0; k < 4; ++k) {
            float4 wq = w1v[j * 4 + k];
            #pragma unroll
            for (int v = 0; v < 4; ++v) {
                acc[v] += wq.x * h1[4*k+0][v] + wq.y * h1[4*k+1][v]
                        + wq.z * h1[4*k+2][v] + wq.w * h1[4*k+3][v];
            }
        }
        float w2j = mlpS[168 + j];
        #pragma unroll
        for (int v = 0; v < 4; ++v) y[v] += w2j * fmaxf(acc[v], 0.f);
    }

    float vw[4];
    #pragma unroll
    for (int v = 0; v < 4; ++v) {
        float m = __fdividef(1.f, 1.f + __expf(-y[v]));
        #pragma unroll
        for (int off = 16; off; off >>= 1) m = fmaxf(m, __shfl_xor(m, off));
        vw[v] = m;
    }

    float wsum = 1e-5f + vw[0] + vw[1] + vw[2] + vw[3];
    float vol = sv[0] * vw[0] + sv[1] * vw[1] + sv[2] * vw[2] + sv[3] * vw[3];
    ws[WS_SIM + ((size_t)(b * Dc + d)) * HWc + p] = __fdividef(vol, wsum);

    if (d < 4)
        out[OUT_VW + ((size_t)b * 4 + d) * HWc + p] = vw[d];
}

// ---------- SHARED TAIL ----------
__global__ __launch_bounds__(256) void conv_kernel(const float* __restrict__ regb,
                                                   float* __restrict__ ws) {
    int p = blockIdx.x * 256 + threadIdx.x;
    int b = blockIdx.y;
    int q = blockIdx.z;          // d-quad: outputs d = 4q..4q+3
    int h = p / Wc, w = p % Wc;

    float kw[27];
    #pragma unroll
    for (int i = 0; i < 27; ++i) kw[i] = ws[WS_KW + i];

    const float* simb = ws + WS_SIM + (size_t)b * Dc * HWc;
    float acc[4] = {0.f, 0.f, 0.f, 0.f};
    #pragma unroll
    for (int e = -1; e <= 4; ++e) {
        int dd = q * 4 + e;
        if (dd < 0 || dd >= Dc) continue;
        float val[3][3];
        #pragma unroll
        for (int i = 0; i < 3; ++i) {
            int hh = h + i - 1;
            #pragma unroll
            for (int j = 0; j < 3; ++j) {
                int wwp = w + j - 1;
                bool ok = ((unsigned)hh < (unsigned)Hc) && ((unsigned)wwp < (unsigned)Wc);
                val[i][j] = ok ? simb[(size_t)dd * HWc + hh * Wc + wwp] : 0.f;
            }
        }
        #pragma unroll
        for (int kd = 0; kd < 3; ++kd) {
            int tgt = e - kd + 1;
            if (tgt < 0 || tgt > 3) continue;
            float hs = 0.f;
            #pragma unroll
            for (int i = 0; i < 3; ++i)
                #pragma unroll
                for (int j = 0; j < 3; ++j)
                    hs += kw[kd * 9 + i * 3 + j] * val[i][j];
            acc[tgt] += hs;
        }
    }
    float bb = regb[0];
    #pragma unroll
    for (int r = 0; r < 4; ++r)
        ws[WS_PRE + ((size_t)(b * Dc + q * 4 + r)) * HWc + p] = acc[r] + bb;
}

__global__ __launch_bounds__(256) void softmax_kernel(const float* __restrict__ dvals,
                                                      const float* __restrict__ ws,
                                                      float* __restrict__ out) {
    int idx = blockIdx.x * 256 + threadIdx.x;   // B*HW*4
    int lane = idx & 63;
    int t = lane >> 4;
    int pw = lane & 15;
    int P = (idx >> 6) * 16 + pw;
    int b = P / HWc, p = P % HWc;

    const float* preb = ws + WS_PRE + (size_t)b * Dc * HWc + p;
    float pr[8];
    #pragma unroll
    for (int k = 0; k < 8; ++k) pr[k] = preb[(size_t)(t * 8 + k) * HWc];

    float m = pr[0]; int am = t * 8;
    #pragma unroll
    for (int k = 1; k < 8; ++k) if (pr[k] > m) { m = pr[k]; am = t * 8 + k; }
    #pragma unroll
    for (int s = 16; s <= 32; s <<= 1) {
        float om = __shfl_xor(m, s);
        int oi = __shfl_xor(am, s);
        if (om > m || (om == m && oi < am)) { m = om; am = oi; }
    }
    float e[8]; float sum = 0.f;
    #pragma unroll
    for (int k = 0; k < 8; ++k) { e[k] = __expf(pr[k] - m); sum += e[k]; }
    #pragma unroll
    for (int s = 16; s <= 32; s <<= 1) sum += __shfl_xor(sum, s);
    float inv = __fdividef(1.f, sum);
    #pragma unroll
    for (int k = 0; k < 8; ++k)
        out[OUT_PROB + ((size_t)(b * Dc + t * 8 + k)) * HWc + p] = e[k] * inv;
    if (t == 0) {
        out[OUT_DEPTH + (size_t)b * HWc + p] = dvals[((size_t)(b * Dc + am)) * HWc + p];
        out[OUT_CONF + (size_t)b * HWc + p] = inv;
    }
}

extern "C" void kernel_launch(void* const* d_in, const int* in_sizes, int n_in,
                              void* d_out, int out_size, void* d_ws, size_t ws_size,
                              hipStream_t stream) {
    const float* features = (const float*)d_in[0];   // (V,B,C,H,W)
    const float* pm       = (const float*)d_in[1];   // (B,V,2,4,4)
    const float* dvals    = (const float*)d_in[2];   // (B,D,H,W)
    const float* pw_w0    = (const float*)d_in[3];
    const float* pw_b0    = (const float*)d_in[4];
    const float* pw_w1    = (const float*)d_in[5];
    const float* pw_b1    = (const float*)d_in[6];
    const float* pw_w2    = (const float*)d_in[7];
    const float* pw_b2    = (const float*)d_in[8];
    const float* reg_w    = (const float*)d_in[9];
    const float* reg_b    = (const float*)d_in[10];
    float* out = (float*)d_out;
    float* ws  = (float*)d_ws;

    prep_kernel<<<1, 64, 0, stream>>>(pm, reg_w, dvals, ws);
    check_unif_kernel<<<(Bc * Dc * HWc) / 256, 256, 0, stream>>>(dvals, ws);
    // fallback path (early-exits when fast path valid)
    transpose_kernel<<<dim3(Vc * Bc, HWc / 32), 256, 0, stream>>>(features, ws);
    // fast path
    mapA_kernel<<<dim3(HWc / 256, 8), 256, 0, stream>>>(features, ws);
    fb_main_kernel<<<Bc * HWc / 8, 256, 0, stream>>>(dvals, pw_w0, pw_b0, pw_w1, pw_b1,
                                                     pw_w2, pw_b2, ws, out);
    viewweight_kernel<<<dim3(Bc * HWc / 256, 4), 256, 0, stream>>>(pw_w0, pw_b0, pw_w1,
                                                                   pw_b1, pw_w2, pw_b2, ws);
    simcombine_kernel<<<dim3(Bc * HWc / 256, 4), 256, 0, stream>>>(ws, out);
    // shared tail
    conv_kernel<<<dim3(HWc / 256, Bc, 8), 256, 0, stream>>>(reg_b, ws);
    softmax_kernel<<<(Bc * HWc * 4) / 256, 256, 0, stream>>>(dvals, ws, out);
}

// Round 6
// 105.821 us; speedup vs baseline: 2.2717x; 1.3476x over previous
//
#include <hip/hip_runtime.h>
#include <math.h>

#define Bc 2
#define Vc 5
#define Cc 32
#define Dc 32
#define Hc 128
#define Wc 160
#define HWc (Hc*Wc)
#define NSLOT 44

// ---- workspace layout (in floats; _I suffixes are int-indexed via (int*)ws) ----
#define WS_RT     0                       // 8 * 12 floats (rot 9 + trans 3)
#define WS_KW     96                      // 27 collapsed conv taps
#define FLAG_I    128                     // int[2]: [128] translation-ok, [129] dvals-uniform
#define NS_I      136                     // int[8]: slots used per (b,v)
#define SHIFT_I   144                     // 8 * NSLOT * 2 ints (dx,dy)
#define WS_TAPID  912                     // 8 bv * 32 d * 8 (4 int ids, wx, wy, pad2)
#define WS_PWL    2960                    // [0] int K; +8: knots[256] (pad 1e30); +264: alpha[161]; +425: beta[161]
#define WS_M      3584                    // fast: 8 * NSLOT * HW maps | fallback: FEATT overlay | later: PRE overlay
#define WS_FEATT  WS_M
#define WS_PRE    WS_M
#define WS_SIM    (WS_M + 8*NSLOT*HWc)    // B * D * HW, d-major
#define WS_VWP    (WS_SIM + Bc*Dc*HWc)    // B * 4v * 8 part * HW partial logit maxes
// end = WS_VWP + Bc*4*8*HWc = 9,833,984 floats (39.3 MB; R1 used 41.9 MB so ws_size covers it)

// ---- output layout (in floats) ----
#define OUT_DEPTH 0
#define OUT_CONF  (Bc*HWc)
#define OUT_PROB  (2*Bc*HWc)
#define OUT_VW    (2*Bc*HWc + Bc*Dc*HWc)

// k0: matrices, translation check, shift/tap tables, collapsed conv kernel
__global__ void prep_kernel(const float* __restrict__ pm, const float* __restrict__ reg_w,
                            const float* __restrict__ dvals, float* __restrict__ ws) {
    __shared__ int okS[8];
    int* wsi = (int*)ws;
    int t = threadIdx.x;
    if (t < Bc * (Vc - 1)) {
        int b = t / (Vc - 1);
        int v = t % (Vc - 1) + 1;
        float Pv[16], P0[16];
        for (int which = 0; which < 2; ++which) {
            int vv = which ? 0 : v;
            const float* E = pm + ((b * Vc + vv) * 2 + 0) * 16;
            const float* K = pm + ((b * Vc + vv) * 2 + 1) * 16;
            float* P = which ? P0 : Pv;
            for (int i = 0; i < 3; ++i)
                for (int j = 0; j < 4; ++j) {
                    float s = 0.f;
                    for (int k = 0; k < 3; ++k) s += K[i*4+k] * E[k*4+j];
                    P[i*4+j] = s;
                }
            for (int j = 0; j < 4; ++j) P[12+j] = E[12+j];
        }
        float A[16], I[16];
        for (int i = 0; i < 16; ++i) { A[i] = P0[i]; I[i] = (i % 5 == 0) ? 1.f : 0.f; }
        for (int col = 0; col < 4; ++col) {
            int piv = col; float best = fabsf(A[col*4+col]);
            for (int r = col+1; r < 4; ++r) { float av = fabsf(A[r*4+col]); if (av > best) { best = av; piv = r; } }
            if (piv != col)
                for (int j = 0; j < 4; ++j) {
                    float tmp = A[col*4+j]; A[col*4+j] = A[piv*4+j]; A[piv*4+j] = tmp;
                    tmp = I[col*4+j]; I[col*4+j] = I[piv*4+j]; I[piv*4+j] = tmp;
                }
            float inv = 1.f / A[col*4+col];
            for (int j = 0; j < 4; ++j) { A[col*4+j] *= inv; I[col*4+j] *= inv; }
            for (int r = 0; r < 4; ++r) if (r != col) {
                float f = A[r*4+col];
                for (int j = 0; j < 4; ++j) { A[r*4+j] -= f * A[col*4+j]; I[r*4+j] -= f * I[col*4+j]; }
            }
        }
        float M[16];
        for (int i = 0; i < 4; ++i)
            for (int j = 0; j < 4; ++j) {
                float s = 0.f;
                for (int k = 0; k < 4; ++k) s += Pv[i*4+k] * I[k*4+j];
                M[i*4+j] = s;
            }
        float* rt = ws + WS_RT + t * 12;
        for (int i = 0; i < 3; ++i)
            for (int j = 0; j < 3; ++j) rt[i*3+j] = M[i*4+j];
        rt[9] = M[3]; rt[10] = M[7]; rt[11] = M[11];

        float t0 = M[3], t1 = M[7], t2 = M[11];
        bool ok = fabsf(M[0]-1.f) < 3e-5f && fabsf(M[1]) < 3e-5f && fabsf(M[2]) < 3e-5f &&
                  fabsf(M[4]) < 3e-5f && fabsf(M[5]-1.f) < 3e-5f && fabsf(M[6]) < 3e-5f &&
                  fabsf(M[8]) < 1e-6f && fabsf(M[9]) < 1e-6f && fabsf(M[10]-1.f) < 1e-6f &&
                  fabsf(t2) < 1e-6f;
        if (ok) {
            int n = 0;
            int pid0 = 0, pid1 = 0, pid2 = 0, pid3 = 0, pix = 0, piy = 0;
            for (int d = 0; d < Dc; ++d) {
                float dv = dvals[(size_t)(b * Dc + d) * HWc];
                float sx = t0 / dv, sy = t1 / dv;
                float fx0 = floorf(sx), fy0 = floorf(sy);
                int ix = (int)fx0, iy = (int)fy0;
                float wx = sx - fx0, wy = sy - fy0;
                int dxi = ix - pix, dyi = iy - piy;
                bool reuse = (d > 0) && dxi >= -1 && dxi <= 1 && dyi >= -1 && dyi <= 1;
                int id0, id1, id2, id3;
                #define GETPREV(tx2, ty2) ((ty2)==0 ? ((tx2)==0 ? pid0 : pid1) : ((tx2)==0 ? pid2 : pid3))
                #define DOTAP(idv, tx, ty) { \
                    int tx2 = (tx) + dxi, ty2 = (ty) + dyi; \
                    if (reuse && tx2 >= 0 && tx2 <= 1 && ty2 >= 0 && ty2 <= 1) idv = GETPREV(tx2, ty2); \
                    else { if (n < NSLOT) { wsi[SHIFT_I + (t*NSLOT + n)*2] = ix + (tx); \
                                            wsi[SHIFT_I + (t*NSLOT + n)*2 + 1] = iy + (ty); } \
                           idv = n++; } }
                DOTAP(id0, 0, 0)
                DOTAP(id1, 1, 0)
                DOTAP(id2, 0, 1)
                DOTAP(id3, 1, 1)
                #undef DOTAP
                #undef GETPREV
                int base = WS_TAPID + (t * Dc + d) * 8;
                wsi[base+0] = id0; wsi[base+1] = id1; wsi[base+2] = id2; wsi[base+3] = id3;
                ws[base+4] = wx; ws[base+5] = wy; ws[base+6] = 0.f; ws[base+7] = 0.f;
                pid0 = id0; pid1 = id1; pid2 = id2; pid3 = id3; pix = ix; piy = iy;
            }
            if (n > NSLOT) ok = false;
            wsi[NS_I + t] = (n > NSLOT) ? 0 : n;
        } else {
            wsi[NS_I + t] = 0;
        }
        okS[t] = ok ? 1 : 0;
    }
    if (t >= 32 && t < 32 + 27) {
        int k = t - 32;
        float s = 0.f;
        for (int c = 0; c < Cc; ++c) s += reg_w[c * 27 + k];
        ws[WS_KW + k] = s;
    }
    __syncthreads();
    if (t == 0) {
        int f = 1;
        for (int i = 0; i < 8; ++i) f &= okS[i];
        wsi[FLAG_I] = f;
        wsi[FLAG_I + 1] = 1;
    }
}

// k0c: build exact piecewise-linear table of the 1->16->8->1 ReLU MLP (pre-sigmoid).
__global__ void pwl_prep_kernel(const float* __restrict__ w0, const float* __restrict__ b0,
                                const float* __restrict__ w1, const float* __restrict__ b1,
                                const float* __restrict__ w2, const float* __restrict__ b2,
                                float* __restrict__ ws) {
    __shared__ float W0[16], B0[16], W1[128], B1[8], W2[8], B2s;
    __shared__ float rawK[160], t0S[16], sortedS[160];
    __shared__ int nrawS;
    int t = threadIdx.x;
    if (t < 16) { W0[t] = w0[t]; B0[t] = b0[t]; }
    if (t < 128) W1[t] = w1[t];
    if (t < 8) { B1[t] = b1[t]; W2[t] = w2[t]; }
    if (t == 0) { B2s = b2[0]; nrawS = 0; }
    __syncthreads();
    // layer-1 knots
    if (t < 16 && W0[t] != 0.f) {
        int i = atomicAdd(&nrawS, 1);
        rawK[i] = -B0[t] / W0[t];
    }
    __syncthreads();
    int n0 = nrawS;
    if (t < n0) {   // rank-sort layer-1 knots -> t0S
        float v = rawK[t]; int r = 0;
        for (int k = 0; k < n0; ++k) { float o = rawK[k]; r += (o < v) || (o == v && k < t); }
        t0S[r] = v;
    }
    __syncthreads();
    if (t < n0) rawK[t] = t0S[t];
    // layer-2 zero crossings: item = j*(n0+1)+m over intervals of t0S
    int nItems = 8 * (n0 + 1);
    if (t < nItems) {
        int j = t / (n0 + 1), m = t % (n0 + 1);
        float se;
        if (n0 == 0) se = 0.f;
        else if (m == 0) se = t0S[0] - 1.f;
        else if (m == n0) se = t0S[n0 - 1] + 1.f;
        else se = 0.5f * (t0S[m - 1] + t0S[m]);
        float aval = B1[j], aslp = 0.f;
        for (int i = 0; i < 16; ++i) {
            float pre = W0[i] * se + B0[i];
            if (pre > 0.f) { aval += W1[j * 16 + i] * pre; aslp += W1[j * 16 + i] * W0[i]; }
        }
        if (aslp != 0.f) {
            float sstar = se - aval / aslp;
            float lo = (m == 0) ? -3e38f : t0S[m - 1];
            float hi = (m == n0) ? 3e38f : t0S[m];
            if (sstar > lo && sstar < hi) { int i2 = atomicAdd(&nrawS, 1); rawK[i2] = sstar; }
        }
    }
    __syncthreads();
    int K = nrawS; if (K > 160) K = 160;   // mathematically K <= 152
    if (t < K) {   // final rank-sort
        float v = rawK[t]; int r = 0;
        for (int k = 0; k < K; ++k) { float o = rawK[k]; r += (o < v) || (o == v && k < t); }
        sortedS[r] = v;
    }
    __syncthreads();
    ws[WS_PWL + 8 + t] = (t < K) ? sortedS[t] : 1e30f;    // 256 knots incl. pad
    if (t <= K) {   // per-segment slope/intercept via analytic active-set
        float se;
        if (K == 0) se = 0.f;
        else if (t == 0) se = sortedS[0] - 1.f;
        else if (t == K) se = sortedS[K - 1] + 1.f;
        else se = 0.5f * (sortedS[t - 1] + sortedS[t]);
        float y = B2s, slp = 0.f;
        for (int j = 0; j < 8; ++j) {
            float aval = B1[j], aslp = 0.f;
            for (int i = 0; i < 16; ++i) {
                float pre = W0[i] * se + B0[i];
                if (pre > 0.f) { aval += W1[j * 16 + i] * pre; aslp += W1[j * 16 + i] * W0[i]; }
            }
            if (aval > 0.f) { y += W2[j] * aval; slp += W2[j] * aslp; }
        }
        ws[WS_PWL + 264 + t] = slp;
        ws[WS_PWL + 425 + t] = y - slp * se;
    }
    if (t == 0) ((int*)ws)[WS_PWL] = K;
}

// k0b: verify depth_values uniform over (h,w); clear flag on mismatch
__global__ void check_unif_kernel(const float* __restrict__ dvals, float* __restrict__ ws) {
    int idx = blockIdx.x * 256 + threadIdx.x;   // < B*D*HW
    int plane = idx / HWc;
    float v = dvals[idx];
    if (v != dvals[(size_t)plane * HWc]) ((int*)ws)[FLAG_I + 1] = 0;
}

// ---------- FAST PATH ----------
// kA: slot maps, slot-split x4 in z for occupancy. thread = pixel; ref[32] in regs.
__global__ __launch_bounds__(256) void mapA_kernel(const float* __restrict__ feat,
                                                   float* __restrict__ ws) {
    const int* wsi = (const int*)ws;
    if (!(wsi[FLAG_I] & wsi[FLAG_I + 1])) return;
    __shared__ int shiftS[NSLOT * 2];
    int bv = blockIdx.y;
    int ns = wsi[NS_I + bv];
    int s0 = blockIdx.z * (NSLOT / 4);
    int s1 = min(ns, s0 + NSLOT / 4);
    if (s0 >= ns) return;
    int b = bv >> 2, vm1 = bv & 3;
    int tid = threadIdx.x;
    if (tid < NSLOT * 2) shiftS[tid] = wsi[SHIFT_I + bv * NSLOT * 2 + tid];
    __syncthreads();

    int p = blockIdx.x * 256 + tid;
    int h = p / Wc, w = p % Wc;

    const float* refp = feat + (size_t)b * Cc * HWc + p;
    const float* srcp = feat + (size_t)((vm1 + 1) * Bc + b) * Cc * HWc;
    float rf[Cc];
    #pragma unroll
    for (int c = 0; c < Cc; ++c) rf[c] = refp[(size_t)c * HWc];

    float* Mout = ws + WS_M + (size_t)bv * NSLOT * HWc + p;
    for (int s = s0; s < s1; ++s) {
        int dx = shiftS[2 * s], dy = shiftS[2 * s + 1];
        int sw = w + dx, sh = h + dy;
        float val = 0.f;
        if (((unsigned)sw < (unsigned)Wc) && ((unsigned)sh < (unsigned)Hc)) {
            const float* sq = srcp + (sh * Wc + sw);
            float a0 = 0.f, a1 = 0.f, a2 = 0.f, a3 = 0.f;
            #pragma unroll
            for (int c = 0; c < Cc; c += 4) {
                a0 += rf[c]     * sq[(size_t)(c)     * HWc];
                a1 += rf[c + 1] * sq[(size_t)(c + 1) * HWc];
                a2 += rf[c + 2] * sq[(size_t)(c + 2) * HWc];
                a3 += rf[c + 3] * sq[(size_t)(c + 3) * HWc];
            }
            val = ((a0 + a1) + (a2 + a3)) * (1.f / 32.f);
        }
        Mout[(size_t)s * HWc] = val;
    }
}

// kB1: view-weight logit partials via PWL table. thread = pixel; d-quad in blockIdx.y.
__global__ __launch_bounds__(256) void viewweight_kernel(float* __restrict__ ws) {
    const int* wsi = (const int*)ws;
    if (!(wsi[FLAG_I] & wsi[FLAG_I + 1])) return;
    __shared__ float knotS[256];
    __shared__ float alphaS[161], betaS[161];
    __shared__ float tapS[128];             // [4 v][4 d][8]

    int tid = threadIdx.x;
    int pg = blockIdx.x * 256 + tid;
    int b = pg / HWc, p = pg % HWc;
    int q = blockIdx.y;                     // d-quad 0..7

    knotS[tid] = ws[WS_PWL + 8 + tid];
    if (tid < 161) { alphaS[tid] = ws[WS_PWL + 264 + tid]; betaS[tid] = ws[WS_PWL + 425 + tid]; }
    if (tid < 128) {
        int v = tid >> 5, dl = (tid >> 3) & 3, f = tid & 7;
        tapS[tid] = ws[WS_TAPID + (((b * 4 + v) * Dc) + q * 4 + dl) * 8 + f];
    }
    __syncthreads();

    float vm[4] = {-1e30f, -1e30f, -1e30f, -1e30f};
    for (int dl = 0; dl < 4; ++dl) {
        #pragma unroll
        for (int v = 0; v < 4; ++v) {
            const float* rec = tapS + ((v * 4 + dl) << 3);
            int i00 = __float_as_int(rec[0]);
            int i10 = __float_as_int(rec[1]);
            int i01 = __float_as_int(rec[2]);
            int i11 = __float_as_int(rec[3]);
            float wx = rec[4], wy = rec[5];
            const float* Mb = ws + WS_M + ((size_t)(b * 4 + v)) * NSLOT * HWc + p;
            float m00 = Mb[(size_t)i00 * HWc];
            float m10 = Mb[(size_t)i10 * HWc];
            float m01 = Mb[(size_t)i01 * HWc];
            float m11 = Mb[(size_t)i11 * HWc];
            float top = m00 + wx * (m10 - m00);
            float bot = m01 + wx * (m11 - m01);
            float s = top + wy * (bot - top);
            // PWL eval: seg = #knots <= s (8-step binary search over padded 256)
            int seg = 0;
            #pragma unroll
            for (int st = 128; st; st >>= 1) {
                int c = seg + st;
                seg = (s >= knotS[c - 1]) ? c : seg;
            }
            float y = fmaf(alphaS[seg], s, betaS[seg]);
            vm[v] = fmaxf(vm[v], y);
        }
    }
    #pragma unroll
    for (int v = 0; v < 4; ++v)
        ws[WS_VWP + ((size_t)((b * 4 + v) * 8 + q)) * HWc + p] = vm[v];
}

// kB2: similarity. thread = pixel; reduce 8 logit partials -> sigmoid -> vw; 4 d per thread.
__global__ __launch_bounds__(256) void simcombine_kernel(float* __restrict__ ws,
                                                         float* __restrict__ out) {
    const int* wsi = (const int*)ws;
    if (!(wsi[FLAG_I] & wsi[FLAG_I + 1])) return;
    __shared__ float tapS[128];

    int tid = threadIdx.x;
    int pg = blockIdx.x * 256 + tid;
    int b = pg / HWc, p = pg % HWc;
    int q = blockIdx.y;                     // d-quad 0..7

    if (tid < 128) {
        int v = tid >> 5, dl = (tid >> 3) & 3, f = tid & 7;
        tapS[tid] = ws[WS_TAPID + (((b * 4 + v) * Dc) + q * 4 + dl) * 8 + f];
    }
    __syncthreads();

    float vw[4];
    float wsum = 1e-5f;
    #pragma unroll
    for (int v = 0; v < 4; ++v) {
        const float* vp = ws + WS_VWP + ((size_t)((b * 4 + v) * 8)) * HWc + p;
        float m = -1e30f;
        #pragma unroll
        for (int k = 0; k < 8; ++k) m = fmaxf(m, vp[(size_t)k * HWc]);
        float sig = __fdividef(1.f, 1.f + __expf(-m));
        vw[v] = sig;
        wsum += sig;
    }
    float invw = __fdividef(1.f, wsum);

    for (int dl = 0; dl < 4; ++dl) {
        float vol = 0.f;
        #pragma unroll
        for (int v = 0; v < 4; ++v) {
            const float* rec = tapS + ((v * 4 + dl) << 3);
            int i00 = __float_as_int(rec[0]);
            int i10 = __float_as_int(rec[1]);
            int i01 = __float_as_int(rec[2]);
            int i11 = __float_as_int(rec[3]);
            float wx = rec[4], wy = rec[5];
            const float* Mb = ws + WS_M + ((size_t)(b * 4 + v)) * NSLOT * HWc + p;
            float m00 = Mb[(size_t)i00 * HWc];
            float m10 = Mb[(size_t)i10 * HWc];
            float m01 = Mb[(size_t)i01 * HWc];
            float m11 = Mb[(size_t)i11 * HWc];
            float top = m00 + wx * (m10 - m00);
            float bot = m01 + wx * (m11 - m01);
            vol += (top + wy * (bot - top)) * vw[v];
        }
        ws[WS_SIM + ((size_t)(b * Dc + q * 4 + dl)) * HWc + p] = vol * invw;
    }
    if (q == 0) {
        #pragma unroll
        for (int v = 0; v < 4; ++v)
            out[OUT_VW + ((size_t)(b * 4 + v)) * HWc + p] = vw[v];
    }
}

// ---------- FALLBACK PATH (generic; gated off when fast path valid) ----------
__global__ void transpose_kernel(const float* __restrict__ feat, float* __restrict__ ws) {
    const int* wsi = (const int*)ws;
    if (wsi[FLAG_I] & wsi[FLAG_I + 1]) return;
    __shared__ float tile[32][33];
    int slab = blockIdx.x;
    int pbase = blockIdx.y * 32;
    int tid = threadIdx.x;
    const float* src = feat + (size_t)slab * Cc * HWc;
    float* dst = ws + WS_FEATT + (size_t)slab * HWc * Cc;
    int cc = tid >> 5, pp = tid & 31;
    #pragma unroll
    for (int i = 0; i < 4; ++i) {
        int c = cc + 8 * i;
        tile[c][pp] = src[(size_t)c * HWc + pbase + pp];
    }
    __syncthreads();
    int c2 = tid & 31, p2 = tid >> 5;
    #pragma unroll
    for (int i = 0; i < 4; ++i) {
        int pq = p2 + 8 * i;
        dst[((size_t)(pbase + pq)) * 32 + c2] = tile[c2][pq];
    }
}

__global__ __launch_bounds__(256) void fb_main_kernel(
        const float* __restrict__ dvals,
        const float* __restrict__ w0, const float* __restrict__ b0,
        const float* __restrict__ w1, const float* __restrict__ b1,
        const float* __restrict__ w2, const float* __restrict__ b2,
        float* __restrict__ ws, float* __restrict__ out) {
    const int* wsi = (const int*)ws;
    if (wsi[FLAG_I] & wsi[FLAG_I + 1]) return;
    __shared__ float mlpS[177];
    __shared__ float rtS[48];

    int bid = blockIdx.x;
    int b = bid / (HWc / 8);
    int pblk = (bid % (HWc / 8)) * 8;
    int tid = threadIdx.x;
    int d = tid & 31;
    int pg = tid >> 5;
    int p = pblk + pg;
    int h = p / Wc, w = p % Wc;

    if (tid < 16) mlpS[tid] = w0[tid];
    else if (tid < 32) mlpS[tid] = b0[tid - 16];
    else if (tid < 160) mlpS[tid] = w1[tid - 32];
    else if (tid < 168) mlpS[tid] = b1[tid - 160];
    else if (tid < 176) mlpS[tid] = w2[tid - 168];
    else if (tid == 176) mlpS[176] = b2[0];
    if (tid >= 192 && tid < 240) rtS[tid - 192] = ws[WS_RT + b * 48 + (tid - 192)];
    __syncthreads();

    const float4* refp = (const float4*)(ws + WS_FEATT + ((size_t)b * HWc + p) * Cc);
    float4 rf[8];
    #pragma unroll
    for (int i = 0; i < 8; ++i) rf[i] = refp[i];

    float depth = dvals[((size_t)(b * Dc + d)) * HWc + p];
    float fx = (float)w, fy = (float)h;

    float sv[4];
    #pragma unroll
    for (int v = 0; v < 4; ++v) {
        const float* rt = rtS + v * 12;
        float px = (rt[0] * fx + rt[1] * fy + rt[2]) * depth + rt[9];
        float py = (rt[3] * fx + rt[4] * fy + rt[5]) * depth + rt[10];
        float pz = (rt[6] * fx + rt[7] * fy + rt[8]) * depth + rt[11];
        float xs = __fdividef(px, pz);
        float ys = __fdividef(py, pz);
        float fx0 = floorf(xs), fy0 = floorf(ys);
        float wx = xs - fx0, wy = ys - fy0;

        const float* featv = ws + WS_FEATT + ((size_t)((v + 1) * Bc + b)) * HWc * Cc;
        float acc = 0.f;
        #pragma unroll
        for (int ty = 0; ty < 2; ++ty) {
            #pragma unroll
            for (int tx = 0; tx < 2; ++tx) {
                float fxt = fx0 + (float)tx;
                float fyt = fy0 + (float)ty;
                bool valid = (fxt >= 0.f) && (fxt <= (float)(Wc - 1)) &&
                             (fyt >= 0.f) && (fyt <= (float)(Hc - 1));
                float wt = (tx ? wx : 1.f - wx) * (ty ? wy : 1.f - wy);
                if (valid) {
                    int ix = (int)fxt, iy = (int)fyt;
                    const float4* fp = (const float4*)(featv + ((size_t)iy * Wc + ix) * Cc);
                    float dot = 0.f;
                    #pragma unroll
                    for (int i = 0; i < 8; ++i) {
                        float4 fv = fp[i];
                        dot += fv.x * rf[i].x + fv.y * rf[i].y + fv.z * rf[i].z + fv.w * rf[i].w;
                    }
                    acc += wt * dot;
                }
            }
        }
        sv[v] = acc * (1.f / (float)Cc);
    }

    float h1[16][4];
    #pragma unroll
    for (int i = 0; i < 16; ++i) {
        float a = mlpS[i], bb = mlpS[16 + i];
        #pragma unroll
        for (int v = 0; v < 4; ++v) h1[i][v] = fmaxf(a * sv[v] + bb, 0.f);
    }
    float bias2 = mlpS[176];
    float y[4] = {bias2, bias2, bias2, bias2};
    const float4* w1v = (const float4*)(mlpS + 32);
    #pragma unroll
    for (int j = 0; j < 8; ++j) {
        float a0 = mlpS[160 + j];
        float acc[4] = {a0, a0, a0, a0};
        #pragma unroll
        for (int k = 0; k < 4; ++k) {
            float4 wq = w1v[j * 4 + k];
            #pragma unroll
            for (int v = 0; v < 4; ++v) {
                acc[v] += wq.x * h1[4*k+0][v] + wq.y * h1[4*k+1][v]
                        + wq.z * h1[4*k+2][v] + wq.w * h1[4*k+3][v];
            }
        }
        float w2j = mlpS[168 + j];
        #pragma unroll
        for (int v = 0; v < 4; ++v) y[v] += w2j * fmaxf(acc[v], 0.f);
    }

    float vw[4];
    #pragma unroll
    for (int v = 0; v < 4; ++v) {
        float m = __fdividef(1.f, 1.f + __expf(-y[v]));
        #pragma unroll
        for (int off = 16; off; off >>= 1) m = fmaxf(m, __shfl_xor(m, off));
        vw[v] = m;
    }

    float wsum = 1e-5f + vw[0] + vw[1] + vw[2] + vw[3];
    float vol = sv[0] * vw[0] + sv[1] * vw[1] + sv[2] * vw[2] + sv[3] * vw[3];
    ws[WS_SIM + ((size_t)(b * Dc + d)) * HWc + p] = __fdividef(vol, wsum);

    if (d < 4)
        out[OUT_VW + ((size_t)b * 4 + d) * HWc + p] = vw[d];
}

// ---------- SHARED TAIL ----------
__global__ __launch_bounds__(256) void conv_kernel(const float* __restrict__ regb,
                                                   float* __restrict__ ws) {
    int p = blockIdx.x * 256 + threadIdx.x;
    int b = blockIdx.y;
    int q = blockIdx.z;
    int h = p / Wc, w = p % Wc;

    float kw[27];
    #pragma unroll
    for (int i = 0; i < 27; ++i) kw[i] = ws[WS_KW + i];

    const float* simb = ws + WS_SIM + (size_t)b * Dc * HWc;
    float acc[4] = {0.f, 0.f, 0.f, 0.f};
    #pragma unroll
    for (int e = -1; e <= 4; ++e) {
        int dd = q * 4 + e;
        if (dd < 0 || dd >= Dc) continue;
        float val[3][3];
        #pragma unroll
        for (int i = 0; i < 3; ++i) {
            int hh = h + i - 1;
            #pragma unroll
            for (int j = 0; j < 3; ++j) {
                int wwp = w + j - 1;
                bool ok = ((unsigned)hh < (unsigned)Hc) && ((unsigned)wwp < (unsigned)Wc);
                val[i][j] = ok ? simb[(size_t)dd * HWc + hh * Wc + wwp] : 0.f;
            }
        }
        #pragma unroll
        for (int kd = 0; kd < 3; ++kd) {
            int tgt = e - kd + 1;
            if (tgt < 0 || tgt > 3) continue;
            float hs = 0.f;
            #pragma unroll
            for (int i = 0; i < 3; ++i)
                #pragma unroll
                for (int j = 0; j < 3; ++j)
                    hs += kw[kd * 9 + i * 3 + j] * val[i][j];
            acc[tgt] += hs;
        }
    }
    float bb = regb[0];
    #pragma unroll
    for (int r = 0; r < 4; ++r)
        ws[WS_PRE + ((size_t)(b * Dc + q * 4 + r)) * HWc + p] = acc[r] + bb;
}

__global__ __launch_bounds__(256) void softmax_kernel(const float* __restrict__ dvals,
                                                      const float* __restrict__ ws,
                                                      float* __restrict__ out) {
    int idx = blockIdx.x * 256 + threadIdx.x;
    int lane = idx & 63;
    int t = lane >> 4;
    int pw = lane & 15;
    int P = (idx >> 6) * 16 + pw;
    int b = P / HWc, p = P % HWc;

    const float* preb = ws + WS_PRE + (size_t)b * Dc * HWc + p;
    float pr[8];
    #pragma unroll
    for (int k = 0; k < 8; ++k) pr[k] = preb[(size_t)(t * 8 + k) * HWc];

    float m = pr[0]; int am = t * 8;
    #pragma unroll
    for (int k = 1; k < 8; ++k) if (pr[k] > m) { m = pr[k]; am = t * 8 + k; }
    #pragma unroll
    for (int s = 16; s <= 32; s <<= 1) {
        float om = __shfl_xor(m, s);
        int oi = __shfl_xor(am, s);
        if (om > m || (om == m && oi < am)) { m = om; am = oi; }
    }
    float e[8]; float sum = 0.f;
    #pragma unroll
    for (int k = 0; k < 8; ++k) { e[k] = __expf(pr[k] - m); sum += e[k]; }
    #pragma unroll
    for (int s = 16; s <= 32; s <<= 1) sum += __shfl_xor(sum, s);
    float inv = __fdividef(1.f, sum);
    #pragma unroll
    for (int k = 0; k < 8; ++k)
        out[OUT_PROB + ((size_t)(b * Dc + t * 8 + k)) * HWc + p] = e[k] * inv;
    if (t == 0) {
        out[OUT_DEPTH + (size_t)b * HWc + p] = dvals[((size_t)(b * Dc + am)) * HWc + p];
        out[OUT_CONF + (size_t)b * HWc + p] = inv;
    }
}

extern "C" void kernel_launch(void* const* d_in, const int* in_sizes, int n_in,
                              void* d_out, int out_size, void* d_ws, size_t ws_size,
                              hipStream_t stream) {
    const float* features = (const float*)d_in[0];   // (V,B,C,H,W)
    const float* pm       = (const float*)d_in[1];   // (B,V,2,4,4)
    const float* dvals    = (const float*)d_in[2];   // (B,D,H,W)
    const float* pw_w0    = (const float*)d_in[3];
    const float* pw_b0    = (const float*)d_in[4];
    const float* pw_w1    = (const float*)d_in[5];
    const float* pw_b1    = (const float*)d_in[6];
    const float* pw_w2    = (const float*)d_in[7];
    const float* pw_b2    = (const float*)d_in[8];
    const float* reg_w    = (const float*)d_in[9];
    const float* reg_b    = (const float*)d_in[10];
    float* out = (float*)d_out;
    float* ws  = (float*)d_ws;

    prep_kernel<<<1, 64, 0, stream>>>(pm, reg_w, dvals, ws);
    pwl_prep_kernel<<<1, 256, 0, stream>>>(pw_w0, pw_b0, pw_w1, pw_b1, pw_w2, pw_b2, ws);
    check_unif_kernel<<<(Bc * Dc * HWc) / 256, 256, 0, stream>>>(dvals, ws);
    // fallback path (early-exits when fast path valid)
    transpose_kernel<<<dim3(Vc * Bc, HWc / 32), 256, 0, stream>>>(features, ws);
    // fast path
    mapA_kernel<<<dim3(HWc / 256, 8, 4), 256, 0, stream>>>(features, ws);
    fb_main_kernel<<<Bc * HWc / 8, 256, 0, stream>>>(dvals, pw_w0, pw_b0, pw_w1, pw_b1,
                                                     pw_w2, pw_b2, ws, out);
    viewweight_kernel<<<dim3(Bc * HWc / 256, 8), 256, 0, stream>>>(ws);
    simcombine_kernel<<<dim3(Bc * HWc / 256, 8), 256, 0, stream>>>(ws, out);
    // shared tail
    conv_kernel<<<dim3(HWc / 256, Bc, 8), 256, 0, stream>>>(reg_b, ws);
    softmax_kernel<<<(Bc * HWc * 4) / 256, 256, 0, stream>>>(dvals, ws, out);
}

// Round 7
// 101.375 us; speedup vs baseline: 2.3713x; 1.0439x over previous
//
#include <hip/hip_runtime.h>
#include <math.h>

#define Bc 2
#define Vc 5
#define Cc 32
#define Dc 32
#define Hc 128
#define Wc 160
#define HWc (Hc*Wc)
#define NSLOT 44
#define TILE_CAP 1024

// ---- workspace layout (in floats; _I suffixes are int-indexed via (int*)ws) ----
#define WS_RT     0                       // 8 * 12 floats (rot 9 + trans 3)
#define WS_KW     96                      // 27 collapsed conv taps
#define FLAG_I    128                     // int[2]: [128] translation-ok, [129] dvals-uniform
#define NS_I      136                     // int[8]: slots used per (b,v)
#define SHIFT_I   144                     // 8 * NSLOT * 2 ints (dx,dy), padded with slot0
#define BBOX_I    856                     // 8 bv * 4 ints: dxmin, dymin, dw, dh
#define WS_TAPID  912                     // 8 bv * 32 d * 8 (4 int ids, wx, wy, pad2)
#define WS_PWL    2960                    // [0] int K; +8: knots[256]; +264: alpha[161]; +425: beta[161]
#define WS_M      3584                    // fast: 8 * NSLOT * HW maps | fallback: FEATT overlay | later: PRE overlay
#define WS_FEATT  WS_M
#define WS_PRE    WS_M
#define WS_SIM    (WS_M + 8*NSLOT*HWc)    // B * D * HW, d-major
#define WS_VWP    (WS_SIM + Bc*Dc*HWc)    // B * 4v * 8 part * HW partial logit maxes

// ---- output layout (in floats) ----
#define OUT_DEPTH 0
#define OUT_CONF  (Bc*HWc)
#define OUT_PROB  (2*Bc*HWc)
#define OUT_VW    (2*Bc*HWc + Bc*Dc*HWc)

// k0: matrices, translation check, shift/tap tables + bbox, collapsed conv kernel
__global__ void prep_kernel(const float* __restrict__ pm, const float* __restrict__ reg_w,
                            const float* __restrict__ dvals, float* __restrict__ ws) {
    __shared__ int okS[8];
    int* wsi = (int*)ws;
    int t = threadIdx.x;
    if (t < Bc * (Vc - 1)) {
        int b = t / (Vc - 1);
        int v = t % (Vc - 1) + 1;
        float Pv[16], P0[16];
        for (int which = 0; which < 2; ++which) {
            int vv = which ? 0 : v;
            const float* E = pm + ((b * Vc + vv) * 2 + 0) * 16;
            const float* K = pm + ((b * Vc + vv) * 2 + 1) * 16;
            float* P = which ? P0 : Pv;
            for (int i = 0; i < 3; ++i)
                for (int j = 0; j < 4; ++j) {
                    float s = 0.f;
                    for (int k = 0; k < 3; ++k) s += K[i*4+k] * E[k*4+j];
                    P[i*4+j] = s;
                }
            for (int j = 0; j < 4; ++j) P[12+j] = E[12+j];
        }
        float A[16], I[16];
        for (int i = 0; i < 16; ++i) { A[i] = P0[i]; I[i] = (i % 5 == 0) ? 1.f : 0.f; }
        for (int col = 0; col < 4; ++col) {
            int piv = col; float best = fabsf(A[col*4+col]);
            for (int r = col+1; r < 4; ++r) { float av = fabsf(A[r*4+col]); if (av > best) { best = av; piv = r; } }
            if (piv != col)
                for (int j = 0; j < 4; ++j) {
                    float tmp = A[col*4+j]; A[col*4+j] = A[piv*4+j]; A[piv*4+j] = tmp;
                    tmp = I[col*4+j]; I[col*4+j] = I[piv*4+j]; I[piv*4+j] = tmp;
                }
            float inv = 1.f / A[col*4+col];
            for (int j = 0; j < 4; ++j) { A[col*4+j] *= inv; I[col*4+j] *= inv; }
            for (int r = 0; r < 4; ++r) if (r != col) {
                float f = A[r*4+col];
                for (int j = 0; j < 4; ++j) { A[r*4+j] -= f * A[col*4+j]; I[r*4+j] -= f * I[col*4+j]; }
            }
        }
        float M[16];
        for (int i = 0; i < 4; ++i)
            for (int j = 0; j < 4; ++j) {
                float s = 0.f;
                for (int k = 0; k < 4; ++k) s += Pv[i*4+k] * I[k*4+j];
                M[i*4+j] = s;
            }
        float* rt = ws + WS_RT + t * 12;
        for (int i = 0; i < 3; ++i)
            for (int j = 0; j < 3; ++j) rt[i*3+j] = M[i*4+j];
        rt[9] = M[3]; rt[10] = M[7]; rt[11] = M[11];

        float t0 = M[3], t1 = M[7], t2 = M[11];
        bool ok = fabsf(M[0]-1.f) < 3e-5f && fabsf(M[1]) < 3e-5f && fabsf(M[2]) < 3e-5f &&
                  fabsf(M[4]) < 3e-5f && fabsf(M[5]-1.f) < 3e-5f && fabsf(M[6]) < 3e-5f &&
                  fabsf(M[8]) < 1e-6f && fabsf(M[9]) < 1e-6f && fabsf(M[10]-1.f) < 1e-6f &&
                  fabsf(t2) < 1e-6f;
        if (ok) {
            int n = 0;
            int pid0 = 0, pid1 = 0, pid2 = 0, pid3 = 0, pix = 0, piy = 0;
            for (int d = 0; d < Dc; ++d) {
                float dv = dvals[(size_t)(b * Dc + d) * HWc];
                float sx = t0 / dv, sy = t1 / dv;
                float fx0 = floorf(sx), fy0 = floorf(sy);
                int ix = (int)fx0, iy = (int)fy0;
                float wx = sx - fx0, wy = sy - fy0;
                int dxi = ix - pix, dyi = iy - piy;
                bool reuse = (d > 0) && dxi >= -1 && dxi <= 1 && dyi >= -1 && dyi <= 1;
                int id0, id1, id2, id3;
                #define GETPREV(tx2, ty2) ((ty2)==0 ? ((tx2)==0 ? pid0 : pid1) : ((tx2)==0 ? pid2 : pid3))
                #define DOTAP(idv, tx, ty) { \
                    int tx2 = (tx) + dxi, ty2 = (ty) + dyi; \
                    if (reuse && tx2 >= 0 && tx2 <= 1 && ty2 >= 0 && ty2 <= 1) idv = GETPREV(tx2, ty2); \
                    else { if (n < NSLOT) { wsi[SHIFT_I + (t*NSLOT + n)*2] = ix + (tx); \
                                            wsi[SHIFT_I + (t*NSLOT + n)*2 + 1] = iy + (ty); } \
                           idv = n++; } }
                DOTAP(id0, 0, 0)
                DOTAP(id1, 1, 0)
                DOTAP(id2, 0, 1)
                DOTAP(id3, 1, 1)
                #undef DOTAP
                #undef GETPREV
                int base = WS_TAPID + (t * Dc + d) * 8;
                wsi[base+0] = id0; wsi[base+1] = id1; wsi[base+2] = id2; wsi[base+3] = id3;
                ws[base+4] = wx; ws[base+5] = wy; ws[base+6] = 0.f; ws[base+7] = 0.f;
                pid0 = id0; pid1 = id1; pid2 = id2; pid3 = id3; pix = ix; piy = iy;
            }
            if (n > NSLOT) ok = false;
            if (ok) {
                // pad unused slots with slot 0 (keeps bbox valid, enables branch-free accumulate)
                int sx0 = wsi[SHIFT_I + t*NSLOT*2], sy0 = wsi[SHIFT_I + t*NSLOT*2 + 1];
                for (int s = n; s < NSLOT; ++s) {
                    wsi[SHIFT_I + (t*NSLOT + s)*2] = sx0;
                    wsi[SHIFT_I + (t*NSLOT + s)*2 + 1] = sy0;
                }
                // bbox over stored slots
                int dxmin = 1 << 28, dxmax = -(1 << 28), dymin = 1 << 28, dymax = -(1 << 28);
                for (int s = 0; s < n; ++s) {
                    int dx = wsi[SHIFT_I + (t*NSLOT + s)*2];
                    int dy = wsi[SHIFT_I + (t*NSLOT + s)*2 + 1];
                    dxmin = min(dxmin, dx); dxmax = max(dxmax, dx);
                    dymin = min(dymin, dy); dymax = max(dymax, dy);
                }
                int dw = 32 + (dxmax - dxmin);
                int dh = 8 + (dymax - dymin);
                if (dw * dh > TILE_CAP) ok = false;
                wsi[BBOX_I + t*4 + 0] = dxmin;
                wsi[BBOX_I + t*4 + 1] = dymin;
                wsi[BBOX_I + t*4 + 2] = dw;
                wsi[BBOX_I + t*4 + 3] = dh;
            }
            wsi[NS_I + t] = ok ? n : 0;
        } else {
            wsi[NS_I + t] = 0;
        }
        okS[t] = ok ? 1 : 0;
    }
    if (t >= 32 && t < 32 + 27) {
        int k = t - 32;
        float s = 0.f;
        for (int c = 0; c < Cc; ++c) s += reg_w[c * 27 + k];
        ws[WS_KW + k] = s;
    }
    __syncthreads();
    if (t == 0) {
        int f = 1;
        for (int i = 0; i < 8; ++i) f &= okS[i];
        wsi[FLAG_I] = f;
        wsi[FLAG_I + 1] = 1;
    }
}

// k0c: build exact piecewise-linear table of the 1->16->8->1 ReLU MLP (pre-sigmoid).
__global__ void pwl_prep_kernel(const float* __restrict__ w0, const float* __restrict__ b0,
                                const float* __restrict__ w1, const float* __restrict__ b1,
                                const float* __restrict__ w2, const float* __restrict__ b2,
                                float* __restrict__ ws) {
    __shared__ float W0[16], B0[16], W1[128], B1[8], W2[8], B2s;
    __shared__ float rawK[160], t0S[16], sortedS[160];
    __shared__ int nrawS;
    int t = threadIdx.x;
    if (t < 16) { W0[t] = w0[t]; B0[t] = b0[t]; }
    if (t < 128) W1[t] = w1[t];
    if (t < 8) { B1[t] = b1[t]; W2[t] = w2[t]; }
    if (t == 0) { B2s = b2[0]; nrawS = 0; }
    __syncthreads();
    if (t < 16 && W0[t] != 0.f) {
        int i = atomicAdd(&nrawS, 1);
        rawK[i] = -B0[t] / W0[t];
    }
    __syncthreads();
    int n0 = nrawS;
    if (t < n0) {
        float v = rawK[t]; int r = 0;
        for (int k = 0; k < n0; ++k) { float o = rawK[k]; r += (o < v) || (o == v && k < t); }
        t0S[r] = v;
    }
    __syncthreads();
    if (t < n0) rawK[t] = t0S[t];
    int nItems = 8 * (n0 + 1);
    if (t < nItems) {
        int j = t / (n0 + 1), m = t % (n0 + 1);
        float se;
        if (n0 == 0) se = 0.f;
        else if (m == 0) se = t0S[0] - 1.f;
        else if (m == n0) se = t0S[n0 - 1] + 1.f;
        else se = 0.5f * (t0S[m - 1] + t0S[m]);
        float aval = B1[j], aslp = 0.f;
        for (int i = 0; i < 16; ++i) {
            float pre = W0[i] * se + B0[i];
            if (pre > 0.f) { aval += W1[j * 16 + i] * pre; aslp += W1[j * 16 + i] * W0[i]; }
        }
        if (aslp != 0.f) {
            float sstar = se - aval / aslp;
            float lo = (m == 0) ? -3e38f : t0S[m - 1];
            float hi = (m == n0) ? 3e38f : t0S[m];
            if (sstar > lo && sstar < hi) { int i2 = atomicAdd(&nrawS, 1); rawK[i2] = sstar; }
        }
    }
    __syncthreads();
    int K = nrawS; if (K > 160) K = 160;
    if (t < K) {
        float v = rawK[t]; int r = 0;
        for (int k = 0; k < K; ++k) { float o = rawK[k]; r += (o < v) || (o == v && k < t); }
        sortedS[r] = v;
    }
    __syncthreads();
    ws[WS_PWL + 8 + t] = (t < K) ? sortedS[t] : 1e30f;
    if (t <= K) {
        float se;
        if (K == 0) se = 0.f;
        else if (t == 0) se = sortedS[0] - 1.f;
        else if (t == K) se = sortedS[K - 1] + 1.f;
        else se = 0.5f * (sortedS[t - 1] + sortedS[t]);
        float y = B2s, slp = 0.f;
        for (int j = 0; j < 8; ++j) {
            float aval = B1[j], aslp = 0.f;
            for (int i = 0; i < 16; ++i) {
                float pre = W0[i] * se + B0[i];
                if (pre > 0.f) { aval += W1[j * 16 + i] * pre; aslp += W1[j * 16 + i] * W0[i]; }
            }
            if (aval > 0.f) { y += W2[j] * aval; slp += W2[j] * aslp; }
        }
        ws[WS_PWL + 264 + t] = slp;
        ws[WS_PWL + 425 + t] = y - slp * se;
    }
    if (t == 0) ((int*)ws)[WS_PWL] = K;
}

// k0b: verify depth_values uniform over (h,w); clear flag on mismatch
__global__ void check_unif_kernel(const float* __restrict__ dvals, float* __restrict__ ws) {
    int idx = blockIdx.x * 256 + threadIdx.x;
    int plane = idx / HWc;
    float v = dvals[idx];
    if (v != dvals[(size_t)plane * HWc]) ((int*)ws)[FLAG_I + 1] = 0;
}

// ---------- FAST PATH ----------
// kA: LDS-tiled correlation. Block = 32x8 px tile of one bv; 8 channel-groups of 4
// staged as float4 dilated tiles in LDS; 44 branch-free accumulators in VGPRs.
__global__ __launch_bounds__(256) void mapA_kernel(const float* __restrict__ feat,
                                                   float* __restrict__ ws) {
    const int* wsi = (const int*)ws;
    if (!(wsi[FLAG_I] & wsi[FLAG_I + 1])) return;
    __shared__ float4 tile[TILE_CAP];
    __shared__ int shiftS[NSLOT * 2];
    __shared__ int metaS[4];

    int bv = blockIdx.y;
    int tid = threadIdx.x;
    if (tid < NSLOT * 2) shiftS[tid] = wsi[SHIFT_I + bv * NSLOT * 2 + tid];
    if (tid >= 96 && tid < 100) metaS[tid - 96] = wsi[BBOX_I + bv * 4 + (tid - 96)];
    __syncthreads();

    int ns = wsi[NS_I + bv];
    int dxmin = metaS[0], dymin = metaS[1], dw = metaS[2], dh = metaS[3];
    int ntile = dw * dh;

    int bx = blockIdx.x % (Wc / 32), by = blockIdx.x / (Wc / 32);
    int tx0 = bx * 32, ty0 = by * 8;
    int lx = tid & 31, ly = tid >> 5;
    int p = (ty0 + ly) * Wc + tx0 + lx;

    int b = bv >> 2, vm1 = bv & 3;
    const float* refp = feat + (size_t)b * Cc * HWc + p;
    const float* srcb = feat + (size_t)((vm1 + 1) * Bc + b) * Cc * HWc;

    int soff[NSLOT];
    #pragma unroll
    for (int s = 0; s < NSLOT; ++s)
        soff[s] = (shiftS[2 * s + 1] - dymin) * dw + (shiftS[2 * s] - dxmin);
    int loff = ly * dw + lx;

    float acc[NSLOT];
    #pragma unroll
    for (int s = 0; s < NSLOT; ++s) acc[s] = 0.f;

    for (int g = 0; g < 8; ++g) {
        const float* rp = refp + (size_t)(4 * g) * HWc;
        float r0 = rp[0];
        float r1 = rp[(size_t)HWc];
        float r2 = rp[(size_t)2 * HWc];
        float r3 = rp[(size_t)3 * HWc];
        __syncthreads();                       // prior reads done before overwrite
        for (int e = tid; e < ntile; e += 256) {
            int r = e / dw, cc = e - r * dw;
            int gx = tx0 + dxmin + cc, gy = ty0 + dymin + r;
            float4 tv = {0.f, 0.f, 0.f, 0.f};
            if ((unsigned)gx < (unsigned)Wc && (unsigned)gy < (unsigned)Hc) {
                const float* sp = srcb + (size_t)(4 * g) * HWc + gy * Wc + gx;
                tv.x = sp[0];
                tv.y = sp[(size_t)HWc];
                tv.z = sp[(size_t)2 * HWc];
                tv.w = sp[(size_t)3 * HWc];
            }
            tile[e] = tv;
        }
        __syncthreads();
        #pragma unroll
        for (int s = 0; s < NSLOT; ++s) {
            float4 tv = tile[soff[s] + loff];
            acc[s] += r0 * tv.x + r1 * tv.y + r2 * tv.z + r3 * tv.w;
        }
    }

    float* Mout = ws + WS_M + (size_t)bv * NSLOT * HWc + p;
    #pragma unroll
    for (int s = 0; s < NSLOT; ++s)
        if (s < ns) Mout[(size_t)s * HWc] = acc[s] * (1.f / 32.f);
}

// kB1: view-weight logit partials via PWL table. thread = pixel; d-quad in blockIdx.y.
__global__ __launch_bounds__(256) void viewweight_kernel(float* __restrict__ ws) {
    const int* wsi = (const int*)ws;
    if (!(wsi[FLAG_I] & wsi[FLAG_I + 1])) return;
    __shared__ float knotS[256];
    __shared__ float alphaS[161], betaS[161];
    __shared__ float tapS[128];

    int tid = threadIdx.x;
    int pg = blockIdx.x * 256 + tid;
    int b = pg / HWc, p = pg % HWc;
    int q = blockIdx.y;

    knotS[tid] = ws[WS_PWL + 8 + tid];
    if (tid < 161) { alphaS[tid] = ws[WS_PWL + 264 + tid]; betaS[tid] = ws[WS_PWL + 425 + tid]; }
    if (tid < 128) {
        int v = tid >> 5, dl = (tid >> 3) & 3, f = tid & 7;
        tapS[tid] = ws[WS_TAPID + (((b * 4 + v) * Dc) + q * 4 + dl) * 8 + f];
    }
    __syncthreads();

    float vm[4] = {-1e30f, -1e30f, -1e30f, -1e30f};
    for (int dl = 0; dl < 4; ++dl) {
        #pragma unroll
        for (int v = 0; v < 4; ++v) {
            const float* rec = tapS + ((v * 4 + dl) << 3);
            int i00 = __float_as_int(rec[0]);
            int i10 = __float_as_int(rec[1]);
            int i01 = __float_as_int(rec[2]);
            int i11 = __float_as_int(rec[3]);
            float wx = rec[4], wy = rec[5];
            const float* Mb = ws + WS_M + ((size_t)(b * 4 + v)) * NSLOT * HWc + p;
            float m00 = Mb[(size_t)i00 * HWc];
            float m10 = Mb[(size_t)i10 * HWc];
            float m01 = Mb[(size_t)i01 * HWc];
            float m11 = Mb[(size_t)i11 * HWc];
            float top = m00 + wx * (m10 - m00);
            float bot = m01 + wx * (m11 - m01);
            float s = top + wy * (bot - top);
            int seg = 0;
            #pragma unroll
            for (int st = 128; st; st >>= 1) {
                int c = seg + st;
                seg = (s >= knotS[c - 1]) ? c : seg;
            }
            float y = fmaf(alphaS[seg], s, betaS[seg]);
            vm[v] = fmaxf(vm[v], y);
        }
    }
    #pragma unroll
    for (int v = 0; v < 4; ++v)
        ws[WS_VWP + ((size_t)((b * 4 + v) * 8 + q)) * HWc + p] = vm[v];
}

// kB2: similarity. thread = pixel; reduce 8 logit partials -> sigmoid -> vw; 4 d per thread.
__global__ __launch_bounds__(256) void simcombine_kernel(float* __restrict__ ws,
                                                         float* __restrict__ out) {
    const int* wsi = (const int*)ws;
    if (!(wsi[FLAG_I] & wsi[FLAG_I + 1])) return;
    __shared__ float tapS[128];

    int tid = threadIdx.x;
    int pg = blockIdx.x * 256 + tid;
    int b = pg / HWc, p = pg % HWc;
    int q = blockIdx.y;

    if (tid < 128) {
        int v = tid >> 5, dl = (tid >> 3) & 3, f = tid & 7;
        tapS[tid] = ws[WS_TAPID + (((b * 4 + v) * Dc) + q * 4 + dl) * 8 + f];
    }
    __syncthreads();

    float vw[4];
    float wsum = 1e-5f;
    #pragma unroll
    for (int v = 0; v < 4; ++v) {
        const float* vp = ws + WS_VWP + ((size_t)((b * 4 + v) * 8)) * HWc + p;
        float m = -1e30f;
        #pragma unroll
        for (int k = 0; k < 8; ++k) m = fmaxf(m, vp[(size_t)k * HWc]);
        float sig = __fdividef(1.f, 1.f + __expf(-m));
        vw[v] = sig;
        wsum += sig;
    }
    float invw = __fdividef(1.f, wsum);

    for (int dl = 0; dl < 4; ++dl) {
        float vol = 0.f;
        #pragma unroll
        for (int v = 0; v < 4; ++v) {
            const float* rec = tapS + ((v * 4 + dl) << 3);
            int i00 = __float_as_int(rec[0]);
            int i10 = __float_as_int(rec[1]);
            int i01 = __float_as_int(rec[2]);
            int i11 = __float_as_int(rec[3]);
            float wx = rec[4], wy = rec[5];
            const float* Mb = ws + WS_M + ((size_t)(b * 4 + v)) * NSLOT * HWc + p;
            float m00 = Mb[(size_t)i00 * HWc];
            float m10 = Mb[(size_t)i10 * HWc];
            float m01 = Mb[(size_t)i01 * HWc];
            float m11 = Mb[(size_t)i11 * HWc];
            float top = m00 + wx * (m10 - m00);
            float bot = m01 + wx * (m11 - m01);
            vol += (top + wy * (bot - top)) * vw[v];
        }
        ws[WS_SIM + ((size_t)(b * Dc + q * 4 + dl)) * HWc + p] = vol * invw;
    }
    if (q == 0) {
        #pragma unroll
        for (int v = 0; v < 4; ++v)
            out[OUT_VW + ((size_t)(b * 4 + v)) * HWc + p] = vw[v];
    }
}

// ---------- FALLBACK PATH (generic; gated off when fast path valid) ----------
__global__ void transpose_kernel(const float* __restrict__ feat, float* __restrict__ ws) {
    const int* wsi = (const int*)ws;
    if (wsi[FLAG_I] & wsi[FLAG_I + 1]) return;
    __shared__ float tile[32][33];
    int slab = blockIdx.x;
    int pbase = blockIdx.y * 32;
    int tid = threadIdx.x;
    const float* src = feat + (size_t)slab * Cc * HWc;
    float* dst = ws + WS_FEATT + (size_t)slab * HWc * Cc;
    int cc = tid >> 5, pp = tid & 31;
    #pragma unroll
    for (int i = 0; i < 4; ++i) {
        int c = cc + 8 * i;
        tile[c][pp] = src[(size_t)c * HWc + pbase + pp];
    }
    __syncthreads();
    int c2 = tid & 31, p2 = tid >> 5;
    #pragma unroll
    for (int i = 0; i < 4; ++i) {
        int pq = p2 + 8 * i;
        dst[((size_t)(pbase + pq)) * 32 + c2] = tile[c2][pq];
    }
}

__global__ __launch_bounds__(256) void fb_main_kernel(
        const float* __restrict__ dvals,
        const float* __restrict__ w0, const float* __restrict__ b0,
        const float* __restrict__ w1, const float* __restrict__ b1,
        const float* __restrict__ w2, const float* __restrict__ b2,
        float* __restrict__ ws, float* __restrict__ out) {
    const int* wsi = (const int*)ws;
    if (wsi[FLAG_I] & wsi[FLAG_I + 1]) return;
    __shared__ float mlpS[177];
    __shared__ float rtS[48];

    int bid = blockIdx.x;
    int b = bid / (HWc / 8);
    int pblk = (bid % (HWc / 8)) * 8;
    int tid = threadIdx.x;
    int d = tid & 31;
    int pg = tid >> 5;
    int p = pblk + pg;
    int h = p / Wc, w = p % Wc;

    if (tid < 16) mlpS[tid] = w0[tid];
    else if (tid < 32) mlpS[tid] = b0[tid - 16];
    else if (tid < 160) mlpS[tid] = w1[tid - 32];
    else if (tid < 168) mlpS[tid] = b1[tid - 160];
    else if (tid < 176) mlpS[tid] = w2[tid - 168];
    else if (tid == 176) mlpS[176] = b2[0];
    if (tid >= 192 && tid < 240) rtS[tid - 192] = ws[WS_RT + b * 48 + (tid - 192)];
    __syncthreads();

    const float4* refp = (const float4*)(ws + WS_FEATT + ((size_t)b * HWc + p) * Cc);
    float4 rf[8];
    #pragma unroll
    for (int i = 0; i < 8; ++i) rf[i] = refp[i];

    float depth = dvals[((size_t)(b * Dc + d)) * HWc + p];
    float fx = (float)w, fy = (float)h;

    float sv[4];
    #pragma unroll
    for (int v = 0; v < 4; ++v) {
        const float* rt = rtS + v * 12;
        float px = (rt[0] * fx + rt[1] * fy + rt[2]) * depth + rt[9];
        float py = (rt[3] * fx + rt[4] * fy + rt[5]) * depth + rt[10];
        float pz = (rt[6] * fx + rt[7] * fy + rt[8]) * depth + rt[11];
        float xs = __fdividef(px, pz);
        float ys = __fdividef(py, pz);
        float fx0 = floorf(xs), fy0 = floorf(ys);
        float wx = xs - fx0, wy = ys - fy0;

        const float* featv = ws + WS_FEATT + ((size_t)((v + 1) * Bc + b)) * HWc * Cc;
        float acc = 0.f;
        #pragma unroll
        for (int ty = 0; ty < 2; ++ty) {
            #pragma unroll
            for (int tx = 0; tx < 2; ++tx) {
                float fxt = fx0 + (float)tx;
                float fyt = fy0 + (float)ty;
                bool valid = (fxt >= 0.f) && (fxt <= (float)(Wc - 1)) &&
                             (fyt >= 0.f) && (fyt <= (float)(Hc - 1));
                float wt = (tx ? wx : 1.f - wx) * (ty ? wy : 1.f - wy);
                if (valid) {
                    int ix = (int)fxt, iy = (int)fyt;
                    const float4* fp = (const float4*)(featv + ((size_t)iy * Wc + ix) * Cc);
                    float dot = 0.f;
                    #pragma unroll
                    for (int i = 0; i < 8; ++i) {
                        float4 fv = fp[i];
                        dot += fv.x * rf[i].x + fv.y * rf[i].y + fv.z * rf[i].z + fv.w * rf[i].w;
                    }
                    acc += wt * dot;
                }
            }
        }
        sv[v] = acc * (1.f / (float)Cc);
    }

    float h1[16][4];
    #pragma unroll
    for (int i = 0; i < 16; ++i) {
        float a = mlpS[i], bb = mlpS[16 + i];
        #pragma unroll
        for (int v = 0; v < 4; ++v) h1[i][v] = fmaxf(a * sv[v] + bb, 0.f);
    }
    float bias2 = mlpS[176];
    float y[4] = {bias2, bias2, bias2, bias2};
    const float4* w1v = (const float4*)(mlpS + 32);
    #pragma unroll
    for (int j = 0; j < 8; ++j) {
        float a0 = mlpS[160 + j];
        float acc[4] = {a0, a0, a0, a0};
        #pragma unroll
        for (int k = 0; k < 4; ++k) {
            float4 wq = w1v[j * 4 + k];
            #pragma unroll
            for (int v = 0; v < 4; ++v) {
                acc[v] += wq.x * h1[4*k+0][v] + wq.y * h1[4*k+1][v]
                        + wq.z * h1[4*k+2][v] + wq.w * h1[4*k+3][v];
            }
        }
        float w2j = mlpS[168 + j];
        #pragma unroll
        for (int v = 0; v < 4; ++v) y[v] += w2j * fmaxf(acc[v], 0.f);
    }

    float vw[4];
    #pragma unroll
    for (int v = 0; v < 4; ++v) {
        float m = __fdividef(1.f, 1.f + __expf(-y[v]));
        #pragma unroll
        for (int off = 16; off; off >>= 1) m = fmaxf(m, __shfl_xor(m, off));
        vw[v] = m;
    }

    float wsum = 1e-5f + vw[0] + vw[1] + vw[2] + vw[3];
    float vol = sv[0] * vw[0] + sv[1] * vw[1] + sv[2] * vw[2] + sv[3] * vw[3];
    ws[WS_SIM + ((size_t)(b * Dc + d)) * HWc + p] = __fdividef(vol, wsum);

    if (d < 4)
        out[OUT_VW + ((size_t)b * 4 + d) * HWc + p] = vw[d];
}

// ---------- SHARED TAIL ----------
__global__ __launch_bounds__(256) void conv_kernel(const float* __restrict__ regb,
                                                   float* __restrict__ ws) {
    int p = blockIdx.x * 256 + threadIdx.x;
    int b = blockIdx.y;
    int q = blockIdx.z;
    int h = p / Wc, w = p % Wc;

    float kw[27];
    #pragma unroll
    for (int i = 0; i < 27; ++i) kw[i] = ws[WS_KW + i];

    const float* simb = ws + WS_SIM + (size_t)b * Dc * HWc;
    float acc[4] = {0.f, 0.f, 0.f, 0.f};
    #pragma unroll
    for (int e = -1; e <= 4; ++e) {
        int dd = q * 4 + e;
        if (dd < 0 || dd >= Dc) continue;
        float val[3][3];
        #pragma unroll
        for (int i = 0; i < 3; ++i) {
            int hh = h + i - 1;
            #pragma unroll
            for (int j = 0; j < 3; ++j) {
                int wwp = w + j - 1;
                bool ok = ((unsigned)hh < (unsigned)Hc) && ((unsigned)wwp < (unsigned)Wc);
                val[i][j] = ok ? simb[(size_t)dd * HWc + hh * Wc + wwp] : 0.f;
            }
        }
        #pragma unroll
        for (int kd = 0; kd < 3; ++kd) {
            int tgt = e - kd + 1;
            if (tgt < 0 || tgt > 3) continue;
            float hs = 0.f;
            #pragma unroll
            for (int i = 0; i < 3; ++i)
                #pragma unroll
                for (int j = 0; j < 3; ++j)
                    hs += kw[kd * 9 + i * 3 + j] * val[i][j];
            acc[tgt] += hs;
        }
    }
    float bb = regb[0];
    #pragma unroll
    for (int r = 0; r < 4; ++r)
        ws[WS_PRE + ((size_t)(b * Dc + q * 4 + r)) * HWc + p] = acc[r] + bb;
}

__global__ __launch_bounds__(256) void softmax_kernel(const float* __restrict__ dvals,
                                                      const float* __restrict__ ws,
                                                      float* __restrict__ out) {
    int idx = blockIdx.x * 256 + threadIdx.x;
    int lane = idx & 63;
    int t = lane >> 4;
    int pw = lane & 15;
    int P = (idx >> 6) * 16 + pw;
    int b = P / HWc, p = P % HWc;

    const float* preb = ws + WS_PRE + (size_t)b * Dc * HWc + p;
    float pr[8];
    #pragma unroll
    for (int k = 0; k < 8; ++k) pr[k] = preb[(size_t)(t * 8 + k) * HWc];

    float m = pr[0]; int am = t * 8;
    #pragma unroll
    for (int k = 1; k < 8; ++k) if (pr[k] > m) { m = pr[k]; am = t * 8 + k; }
    #pragma unroll
    for (int s = 16; s <= 32; s <<= 1) {
        float om = __shfl_xor(m, s);
        int oi = __shfl_xor(am, s);
        if (om > m || (om == m && oi < am)) { m = om; am = oi; }
    }
    float e[8]; float sum = 0.f;
    #pragma unroll
    for (int k = 0; k < 8; ++k) { e[k] = __expf(pr[k] - m); sum += e[k]; }
    #pragma unroll
    for (int s = 16; s <= 32; s <<= 1) sum += __shfl_xor(sum, s);
    float inv = __fdividef(1.f, sum);
    #pragma unroll
    for (int k = 0; k < 8; ++k)
        out[OUT_PROB + ((size_t)(b * Dc + t * 8 + k)) * HWc + p] = e[k] * inv;
    if (t == 0) {
        out[OUT_DEPTH + (size_t)b * HWc + p] = dvals[((size_t)(b * Dc + am)) * HWc + p];
        out[OUT_CONF + (size_t)b * HWc + p] = inv;
    }
}

extern "C" void kernel_launch(void* const* d_in, const int* in_sizes, int n_in,
                              void* d_out, int out_size, void* d_ws, size_t ws_size,
                              hipStream_t stream) {
    const float* features = (const float*)d_in[0];   // (V,B,C,H,W)
    const float* pm       = (const float*)d_in[1];   // (B,V,2,4,4)
    const float* dvals    = (const float*)d_in[2];   // (B,D,H,W)
    const float* pw_w0    = (const float*)d_in[3];
    const float* pw_b0    = (const float*)d_in[4];
    const float* pw_w1    = (const float*)d_in[5];
    const float* pw_b1    = (const float*)d_in[6];
    const float* pw_w2    = (const float*)d_in[7];
    const float* pw_b2    = (const float*)d_in[8];
    const float* reg_w    = (const float*)d_in[9];
    const float* reg_b    = (const float*)d_in[10];
    float* out = (float*)d_out;
    float* ws  = (float*)d_ws;

    prep_kernel<<<1, 64, 0, stream>>>(pm, reg_w, dvals, ws);
    pwl_prep_kernel<<<1, 256, 0, stream>>>(pw_w0, pw_b0, pw_w1, pw_b1, pw_w2, pw_b2, ws);
    check_unif_kernel<<<(Bc * Dc * HWc) / 256, 256, 0, stream>>>(dvals, ws);
    // fallback path (early-exits when fast path valid)
    transpose_kernel<<<dim3(Vc * Bc, HWc / 32), 256, 0, stream>>>(features, ws);
    // fast path
    mapA_kernel<<<dim3((Wc / 32) * (Hc / 8), 8), 256, 0, stream>>>(features, ws);
    fb_main_kernel<<<Bc * HWc / 8, 256, 0, stream>>>(dvals, pw_w0, pw_b0, pw_w1, pw_b1,
                                                     pw_w2, pw_b2, ws, out);
    viewweight_kernel<<<dim3(Bc * HWc / 256, 8), 256, 0, stream>>>(ws);
    simcombine_kernel<<<dim3(Bc * HWc / 256, 8), 256, 0, stream>>>(ws, out);
    // shared tail
    conv_kernel<<<dim3(HWc / 256, Bc, 8), 256, 0, stream>>>(reg_b, ws);
    softmax_kernel<<<(Bc * HWc * 4) / 256, 256, 0, stream>>>(dvals, ws, out);
}

// Round 8
// 99.912 us; speedup vs baseline: 2.4060x; 1.0146x over previous
//
#include <hip/hip_runtime.h>
#include <math.h>

#define Bc 2
#define Vc 5
#define Cc 32
#define Dc 32
#define Hc 128
#define Wc 160
#define HWc (Hc*Wc)
#define NSLOT 44
#define TILE_CAP 1024

// ---- workspace layout (in floats; _I suffixes are int-indexed via (int*)ws) ----
#define WS_RT     0                       // 8 * 12 floats (rot 9 + trans 3)
#define WS_KW     96                      // 27 collapsed conv taps
#define FLAG_I    128                     // int[2]: [128] translation-ok, [129] dvals-uniform
#define NS_I      136                     // int[8]: slots used per (b,v)
#define SHIFT_I   144                     // 8 * NSLOT * 2 ints (dx,dy), padded with slot0
#define BBOX_I    856                     // 8 bv * 4 ints: dxmin, dymin, dw, dh
#define WS_TAPID  912                     // 8 bv * 32 d * 8 (4 int ids, wx, wy, pad2)
#define WS_PWL    2960                    // [0] int K; +8: knots[256]; +264: alpha[161]; +425: beta[161]
#define WS_M      3584                    // fast: 8 * NSLOT * HW maps | fallback: FEATT overlay
#define WS_FEATT  WS_M
#define WS_SIM    (WS_M + 8*NSLOT*HWc)    // B * D * HW, d-major

// ---- output layout (in floats) ----
#define OUT_DEPTH 0
#define OUT_CONF  (Bc*HWc)
#define OUT_PROB  (2*Bc*HWc)
#define OUT_VW    (2*Bc*HWc + Bc*Dc*HWc)

// k0: matrices, translation check, shift/tap tables + bbox, collapsed conv kernel
__global__ void prep_kernel(const float* __restrict__ pm, const float* __restrict__ reg_w,
                            const float* __restrict__ dvals, float* __restrict__ ws) {
    __shared__ int okS[8];
    int* wsi = (int*)ws;
    int t = threadIdx.x;
    if (t < Bc * (Vc - 1)) {
        int b = t / (Vc - 1);
        int v = t % (Vc - 1) + 1;
        float Pv[16], P0[16];
        for (int which = 0; which < 2; ++which) {
            int vv = which ? 0 : v;
            const float* E = pm + ((b * Vc + vv) * 2 + 0) * 16;
            const float* K = pm + ((b * Vc + vv) * 2 + 1) * 16;
            float* P = which ? P0 : Pv;
            for (int i = 0; i < 3; ++i)
                for (int j = 0; j < 4; ++j) {
                    float s = 0.f;
                    for (int k = 0; k < 3; ++k) s += K[i*4+k] * E[k*4+j];
                    P[i*4+j] = s;
                }
            for (int j = 0; j < 4; ++j) P[12+j] = E[12+j];
        }
        float A[16], I[16];
        for (int i = 0; i < 16; ++i) { A[i] = P0[i]; I[i] = (i % 5 == 0) ? 1.f : 0.f; }
        for (int col = 0; col < 4; ++col) {
            int piv = col; float best = fabsf(A[col*4+col]);
            for (int r = col+1; r < 4; ++r) { float av = fabsf(A[r*4+col]); if (av > best) { best = av; piv = r; } }
            if (piv != col)
                for (int j = 0; j < 4; ++j) {
                    float tmp = A[col*4+j]; A[col*4+j] = A[piv*4+j]; A[piv*4+j] = tmp;
                    tmp = I[col*4+j]; I[col*4+j] = I[piv*4+j]; I[piv*4+j] = tmp;
                }
            float inv = 1.f / A[col*4+col];
            for (int j = 0; j < 4; ++j) { A[col*4+j] *= inv; I[col*4+j] *= inv; }
            for (int r = 0; r < 4; ++r) if (r != col) {
                float f = A[r*4+col];
                for (int j = 0; j < 4; ++j) { A[r*4+j] -= f * A[col*4+j]; I[r*4+j] -= f * I[col*4+j]; }
            }
        }
        float M[16];
        for (int i = 0; i < 4; ++i)
            for (int j = 0; j < 4; ++j) {
                float s = 0.f;
                for (int k = 0; k < 4; ++k) s += Pv[i*4+k] * I[k*4+j];
                M[i*4+j] = s;
            }
        float* rt = ws + WS_RT + t * 12;
        for (int i = 0; i < 3; ++i)
            for (int j = 0; j < 3; ++j) rt[i*3+j] = M[i*4+j];
        rt[9] = M[3]; rt[10] = M[7]; rt[11] = M[11];

        float t0 = M[3], t1 = M[7], t2 = M[11];
        bool ok = fabsf(M[0]-1.f) < 3e-5f && fabsf(M[1]) < 3e-5f && fabsf(M[2]) < 3e-5f &&
                  fabsf(M[4]) < 3e-5f && fabsf(M[5]-1.f) < 3e-5f && fabsf(M[6]) < 3e-5f &&
                  fabsf(M[8]) < 1e-6f && fabsf(M[9]) < 1e-6f && fabsf(M[10]-1.f) < 1e-6f &&
                  fabsf(t2) < 1e-6f;
        if (ok) {
            int n = 0;
            int pid0 = 0, pid1 = 0, pid2 = 0, pid3 = 0, pix = 0, piy = 0;
            for (int d = 0; d < Dc; ++d) {
                float dv = dvals[(size_t)(b * Dc + d) * HWc];
                float sx = t0 / dv, sy = t1 / dv;
                float fx0 = floorf(sx), fy0 = floorf(sy);
                int ix = (int)fx0, iy = (int)fy0;
                float wx = sx - fx0, wy = sy - fy0;
                int dxi = ix - pix, dyi = iy - piy;
                bool reuse = (d > 0) && dxi >= -1 && dxi <= 1 && dyi >= -1 && dyi <= 1;
                int id0, id1, id2, id3;
                #define GETPREV(tx2, ty2) ((ty2)==0 ? ((tx2)==0 ? pid0 : pid1) : ((tx2)==0 ? pid2 : pid3))
                #define DOTAP(idv, tx, ty) { \
                    int tx2 = (tx) + dxi, ty2 = (ty) + dyi; \
                    if (reuse && tx2 >= 0 && tx2 <= 1 && ty2 >= 0 && ty2 <= 1) idv = GETPREV(tx2, ty2); \
                    else { if (n < NSLOT) { wsi[SHIFT_I + (t*NSLOT + n)*2] = ix + (tx); \
                                            wsi[SHIFT_I + (t*NSLOT + n)*2 + 1] = iy + (ty); } \
                           idv = n++; } }
                DOTAP(id0, 0, 0)
                DOTAP(id1, 1, 0)
                DOTAP(id2, 0, 1)
                DOTAP(id3, 1, 1)
                #undef DOTAP
                #undef GETPREV
                int base = WS_TAPID + (t * Dc + d) * 8;
                wsi[base+0] = id0; wsi[base+1] = id1; wsi[base+2] = id2; wsi[base+3] = id3;
                ws[base+4] = wx; ws[base+5] = wy; ws[base+6] = 0.f; ws[base+7] = 0.f;
                pid0 = id0; pid1 = id1; pid2 = id2; pid3 = id3; pix = ix; piy = iy;
            }
            if (n > NSLOT) ok = false;
            if (ok) {
                int sx0 = wsi[SHIFT_I + t*NSLOT*2], sy0 = wsi[SHIFT_I + t*NSLOT*2 + 1];
                for (int s = n; s < NSLOT; ++s) {
                    wsi[SHIFT_I + (t*NSLOT + s)*2] = sx0;
                    wsi[SHIFT_I + (t*NSLOT + s)*2 + 1] = sy0;
                }
                int dxmin = 1 << 28, dxmax = -(1 << 28), dymin = 1 << 28, dymax = -(1 << 28);
                for (int s = 0; s < n; ++s) {
                    int dx = wsi[SHIFT_I + (t*NSLOT + s)*2];
                    int dy = wsi[SHIFT_I + (t*NSLOT + s)*2 + 1];
                    dxmin = min(dxmin, dx); dxmax = max(dxmax, dx);
                    dymin = min(dymin, dy); dymax = max(dymax, dy);
                }
                int dw = 32 + (dxmax - dxmin);
                int dh = 8 + (dymax - dymin);
                if (dw * dh > TILE_CAP) ok = false;
                wsi[BBOX_I + t*4 + 0] = dxmin;
                wsi[BBOX_I + t*4 + 1] = dymin;
                wsi[BBOX_I + t*4 + 2] = dw;
                wsi[BBOX_I + t*4 + 3] = dh;
            }
            wsi[NS_I + t] = ok ? n : 0;
        } else {
            wsi[NS_I + t] = 0;
        }
        okS[t] = ok ? 1 : 0;
    }
    if (t >= 32 && t < 32 + 27) {
        int k = t - 32;
        float s = 0.f;
        for (int c = 0; c < Cc; ++c) s += reg_w[c * 27 + k];
        ws[WS_KW + k] = s;
    }
    __syncthreads();
    if (t == 0) {
        int f = 1;
        for (int i = 0; i < 8; ++i) f &= okS[i];
        wsi[FLAG_I] = f;
        wsi[FLAG_I + 1] = 1;
    }
}

// k0c: build exact piecewise-linear table of the 1->16->8->1 ReLU MLP (pre-sigmoid).
__global__ void pwl_prep_kernel(const float* __restrict__ w0, const float* __restrict__ b0,
                                const float* __restrict__ w1, const float* __restrict__ b1,
                                const float* __restrict__ w2, const float* __restrict__ b2,
                                float* __restrict__ ws) {
    __shared__ float W0[16], B0[16], W1[128], B1[8], W2[8], B2s;
    __shared__ float rawK[160], t0S[16], sortedS[160];
    __shared__ int nrawS;
    int t = threadIdx.x;
    if (t < 16) { W0[t] = w0[t]; B0[t] = b0[t]; }
    if (t < 128) W1[t] = w1[t];
    if (t < 8) { B1[t] = b1[t]; W2[t] = w2[t]; }
    if (t == 0) { B2s = b2[0]; nrawS = 0; }
    __syncthreads();
    if (t < 16 && W0[t] != 0.f) {
        int i = atomicAdd(&nrawS, 1);
        rawK[i] = -B0[t] / W0[t];
    }
    __syncthreads();
    int n0 = nrawS;
    if (t < n0) {
        float v = rawK[t]; int r = 0;
        for (int k = 0; k < n0; ++k) { float o = rawK[k]; r += (o < v) || (o == v && k < t); }
        t0S[r] = v;
    }
    __syncthreads();
    if (t < n0) rawK[t] = t0S[t];
    int nItems = 8 * (n0 + 1);
    if (t < nItems) {
        int j = t / (n0 + 1), m = t % (n0 + 1);
        float se;
        if (n0 == 0) se = 0.f;
        else if (m == 0) se = t0S[0] - 1.f;
        else if (m == n0) se = t0S[n0 - 1] + 1.f;
        else se = 0.5f * (t0S[m - 1] + t0S[m]);
        float aval = B1[j], aslp = 0.f;
        for (int i = 0; i < 16; ++i) {
            float pre = W0[i] * se + B0[i];
            if (pre > 0.f) { aval += W1[j * 16 + i] * pre; aslp += W1[j * 16 + i] * W0[i]; }
        }
        if (aslp != 0.f) {
            float sstar = se - aval / aslp;
            float lo = (m == 0) ? -3e38f : t0S[m - 1];
            float hi = (m == n0) ? 3e38f : t0S[m];
            if (sstar > lo && sstar < hi) { int i2 = atomicAdd(&nrawS, 1); rawK[i2] = sstar; }
        }
    }
    __syncthreads();
    int K = nrawS; if (K > 160) K = 160;
    if (t < K) {
        float v = rawK[t]; int r = 0;
        for (int k = 0; k < K; ++k) { float o = rawK[k]; r += (o < v) || (o == v && k < t); }
        sortedS[r] = v;
    }
    __syncthreads();
    ws[WS_PWL + 8 + t] = (t < K) ? sortedS[t] : 1e30f;
    if (t <= K) {
        float se;
        if (K == 0) se = 0.f;
        else if (t == 0) se = sortedS[0] - 1.f;
        else if (t == K) se = sortedS[K - 1] + 1.f;
        else se = 0.5f * (sortedS[t - 1] + sortedS[t]);
        float y = B2s, slp = 0.f;
        for (int j = 0; j < 8; ++j) {
            float aval = B1[j], aslp = 0.f;
            for (int i = 0; i < 16; ++i) {
                float pre = W0[i] * se + B0[i];
                if (pre > 0.f) { aval += W1[j * 16 + i] * pre; aslp += W1[j * 16 + i] * W0[i]; }
            }
            if (aval > 0.f) { y += W2[j] * aval; slp += W2[j] * aslp; }
        }
        ws[WS_PWL + 264 + t] = slp;
        ws[WS_PWL + 425 + t] = y - slp * se;
    }
    if (t == 0) ((int*)ws)[WS_PWL] = K;
}

// k0b: verify depth_values uniform over (h,w); clear flag on mismatch
__global__ void check_unif_kernel(const float* __restrict__ dvals, float* __restrict__ ws) {
    int idx = blockIdx.x * 256 + threadIdx.x;
    int plane = idx / HWc;
    float v = dvals[idx];
    if (v != dvals[(size_t)plane * HWc]) ((int*)ws)[FLAG_I + 1] = 0;
}

// ---------- FAST PATH ----------
// kA: LDS-tiled correlation. Block = 32x8 px tile of one bv; 8 channel-groups of 4
// staged as float4 dilated tiles in LDS; 44 branch-free accumulators in VGPRs.
__global__ __launch_bounds__(256) void mapA_kernel(const float* __restrict__ feat,
                                                   float* __restrict__ ws) {
    const int* wsi = (const int*)ws;
    if (!(wsi[FLAG_I] & wsi[FLAG_I + 1])) return;
    __shared__ float4 tile[TILE_CAP];
    __shared__ int shiftS[NSLOT * 2];
    __shared__ int metaS[4];

    int bv = blockIdx.y;
    int tid = threadIdx.x;
    if (tid < NSLOT * 2) shiftS[tid] = wsi[SHIFT_I + bv * NSLOT * 2 + tid];
    if (tid >= 96 && tid < 100) metaS[tid - 96] = wsi[BBOX_I + bv * 4 + (tid - 96)];
    __syncthreads();

    int ns = wsi[NS_I + bv];
    int dxmin = metaS[0], dymin = metaS[1], dw = metaS[2], dh = metaS[3];
    int ntile = dw * dh;

    int bx = blockIdx.x % (Wc / 32), by = blockIdx.x / (Wc / 32);
    int tx0 = bx * 32, ty0 = by * 8;
    int lx = tid & 31, ly = tid >> 5;
    int p = (ty0 + ly) * Wc + tx0 + lx;

    int b = bv >> 2, vm1 = bv & 3;
    const float* refp = feat + (size_t)b * Cc * HWc + p;
    const float* srcb = feat + (size_t)((vm1 + 1) * Bc + b) * Cc * HWc;

    int soff[NSLOT];
    #pragma unroll
    for (int s = 0; s < NSLOT; ++s)
        soff[s] = (shiftS[2 * s + 1] - dymin) * dw + (shiftS[2 * s] - dxmin);
    int loff = ly * dw + lx;

    float acc[NSLOT];
    #pragma unroll
    for (int s = 0; s < NSLOT; ++s) acc[s] = 0.f;

    for (int g = 0; g < 8; ++g) {
        const float* rp = refp + (size_t)(4 * g) * HWc;
        float r0 = rp[0];
        float r1 = rp[(size_t)HWc];
        float r2 = rp[(size_t)2 * HWc];
        float r3 = rp[(size_t)3 * HWc];
        __syncthreads();
        for (int e = tid; e < ntile; e += 256) {
            int r = e / dw, cc = e - r * dw;
            int gx = tx0 + dxmin + cc, gy = ty0 + dymin + r;
            float4 tv = {0.f, 0.f, 0.f, 0.f};
            if ((unsigned)gx < (unsigned)Wc && (unsigned)gy < (unsigned)Hc) {
                const float* sp = srcb + (size_t)(4 * g) * HWc + gy * Wc + gx;
                tv.x = sp[0];
                tv.y = sp[(size_t)HWc];
                tv.z = sp[(size_t)2 * HWc];
                tv.w = sp[(size_t)3 * HWc];
            }
            tile[e] = tv;
        }
        __syncthreads();
        #pragma unroll
        for (int s = 0; s < NSLOT; ++s) {
            float4 tv = tile[soff[s] + loff];
            acc[s] += r0 * tv.x + r1 * tv.y + r2 * tv.z + r3 * tv.w;
        }
    }

    float* Mout = ws + WS_M + (size_t)bv * NSLOT * HWc + p;
    #pragma unroll
    for (int s = 0; s < NSLOT; ++s)
        if (s < ns) Mout[(size_t)s * HWc] = acc[s] * (1.f / 32.f);
}

// kB: fused view-weight + similarity. Block = 64 px x 4 d-octs. Phase 1: PWL logit
// maxes per oct; LDS cross-oct reduce -> vw. Phase 2: re-gather, combine, write sim.
__global__ __launch_bounds__(256) void combine_kernel(float* __restrict__ ws,
                                                      float* __restrict__ out) {
    const int* wsi = (const int*)ws;
    if (!(wsi[FLAG_I] & wsi[FLAG_I + 1])) return;
    __shared__ float knotS[256];
    __shared__ float alphaS[161], betaS[161];
    __shared__ float tapS[4 * Dc * 8];      // [4 v][32 d][8]
    __shared__ float redS[4][4][64];        // [oct][v][px]

    int tid = threadIdx.x;
    int px = tid & 63, oct = tid >> 6;
    int pg = blockIdx.x * 64 + px;
    int b = pg / HWc, p = pg % HWc;         // b uniform per block (HWc % 64 == 0)

    knotS[tid] = ws[WS_PWL + 8 + tid];
    if (tid < 161) { alphaS[tid] = ws[WS_PWL + 264 + tid]; betaS[tid] = ws[WS_PWL + 425 + tid]; }
    #pragma unroll
    for (int k = 0; k < 4; ++k)
        tapS[tid + k * 256] = ws[WS_TAPID + b * (4 * Dc * 8) + tid + k * 256];
    __syncthreads();

    // phase 1: per-oct logit max per view
    float vm[4] = {-1e30f, -1e30f, -1e30f, -1e30f};
    for (int dl = 0; dl < 8; ++dl) {
        int d = oct * 8 + dl;
        #pragma unroll
        for (int v = 0; v < 4; ++v) {
            const float* rec = tapS + ((v * Dc + d) << 3);
            int i00 = __float_as_int(rec[0]);
            int i10 = __float_as_int(rec[1]);
            int i01 = __float_as_int(rec[2]);
            int i11 = __float_as_int(rec[3]);
            float wx = rec[4], wy = rec[5];
            const float* Mb = ws + WS_M + ((size_t)(b * 4 + v)) * NSLOT * HWc + p;
            float m00 = Mb[(size_t)i00 * HWc];
            float m10 = Mb[(size_t)i10 * HWc];
            float m01 = Mb[(size_t)i01 * HWc];
            float m11 = Mb[(size_t)i11 * HWc];
            float top = m00 + wx * (m10 - m00);
            float bot = m01 + wx * (m11 - m01);
            float s = top + wy * (bot - top);
            int seg = 0;
            #pragma unroll
            for (int st = 128; st; st >>= 1) {
                int c = seg + st;
                seg = (s >= knotS[c - 1]) ? c : seg;
            }
            float y = fmaf(alphaS[seg], s, betaS[seg]);
            vm[v] = fmaxf(vm[v], y);
        }
    }
    #pragma unroll
    for (int v = 0; v < 4; ++v) redS[oct][v][px] = vm[v];
    __syncthreads();

    float vw[4];
    float wsum = 1e-5f;
    #pragma unroll
    for (int v = 0; v < 4; ++v) {
        float m = fmaxf(fmaxf(redS[0][v][px], redS[1][v][px]),
                        fmaxf(redS[2][v][px], redS[3][v][px]));
        float sig = __fdividef(1.f, 1.f + __expf(-m));
        vw[v] = sig;
        wsum += sig;
    }
    float invw = __fdividef(1.f, wsum);

    // phase 2: re-gather, combine, write sim (d-major)
    for (int dl = 0; dl < 8; ++dl) {
        int d = oct * 8 + dl;
        float vol = 0.f;
        #pragma unroll
        for (int v = 0; v < 4; ++v) {
            const float* rec = tapS + ((v * Dc + d) << 3);
            int i00 = __float_as_int(rec[0]);
            int i10 = __float_as_int(rec[1]);
            int i01 = __float_as_int(rec[2]);
            int i11 = __float_as_int(rec[3]);
            float wx = rec[4], wy = rec[5];
            const float* Mb = ws + WS_M + ((size_t)(b * 4 + v)) * NSLOT * HWc + p;
            float m00 = Mb[(size_t)i00 * HWc];
            float m10 = Mb[(size_t)i10 * HWc];
            float m01 = Mb[(size_t)i01 * HWc];
            float m11 = Mb[(size_t)i11 * HWc];
            float top = m00 + wx * (m10 - m00);
            float bot = m01 + wx * (m11 - m01);
            vol += (top + wy * (bot - top)) * vw[v];
        }
        ws[WS_SIM + ((size_t)(b * Dc + d)) * HWc + p] = vol * invw;
    }
    if (oct == 0) {
        #pragma unroll
        for (int v = 0; v < 4; ++v)
            out[OUT_VW + ((size_t)(b * 4 + v)) * HWc + p] = vw[v];
    }
}

// ---------- FALLBACK PATH (generic; gated off when fast path valid) ----------
__global__ void transpose_kernel(const float* __restrict__ feat, float* __restrict__ ws) {
    const int* wsi = (const int*)ws;
    if (wsi[FLAG_I] & wsi[FLAG_I + 1]) return;
    __shared__ float tile[32][33];
    int slab = blockIdx.x;
    int pbase = blockIdx.y * 32;
    int tid = threadIdx.x;
    const float* src = feat + (size_t)slab * Cc * HWc;
    float* dst = ws + WS_FEATT + (size_t)slab * HWc * Cc;
    int cc = tid >> 5, pp = tid & 31;
    #pragma unroll
    for (int i = 0; i < 4; ++i) {
        int c = cc + 8 * i;
        tile[c][pp] = src[(size_t)c * HWc + pbase + pp];
    }
    __syncthreads();
    int c2 = tid & 31, p2 = tid >> 5;
    #pragma unroll
    for (int i = 0; i < 4; ++i) {
        int pq = p2 + 8 * i;
        dst[((size_t)(pbase + pq)) * 32 + c2] = tile[c2][pq];
    }
}

__global__ __launch_bounds__(256) void fb_main_kernel(
        const float* __restrict__ dvals,
        const float* __restrict__ w0, const float* __restrict__ b0,
        const float* __restrict__ w1, const float* __restrict__ b1,
        const float* __restrict__ w2, const float* __restrict__ b2,
        float* __restrict__ ws, float* __restrict__ out) {
    const int* wsi = (const int*)ws;
    if (wsi[FLAG_I] & wsi[FLAG_I + 1]) return;
    __shared__ float mlpS[177];
    __shared__ float rtS[48];

    int bid = blockIdx.x;
    int b = bid / (HWc / 8);
    int pblk = (bid % (HWc / 8)) * 8;
    int tid = threadIdx.x;
    int d = tid & 31;
    int pg = tid >> 5;
    int p = pblk + pg;
    int h = p / Wc, w = p % Wc;

    if (tid < 16) mlpS[tid] = w0[tid];
    else if (tid < 32) mlpS[tid] = b0[tid - 16];
    else if (tid < 160) mlpS[tid] = w1[tid - 32];
    else if (tid < 168) mlpS[tid] = b1[tid - 160];
    else if (tid < 176) mlpS[tid] = w2[tid - 168];
    else if (tid == 176) mlpS[176] = b2[0];
    if (tid >= 192 && tid < 240) rtS[tid - 192] = ws[WS_RT + b * 48 + (tid - 192)];
    __syncthreads();

    const float4* refp = (const float4*)(ws + WS_FEATT + ((size_t)b * HWc + p) * Cc);
    float4 rf[8];
    #pragma unroll
    for (int i = 0; i < 8; ++i) rf[i] = refp[i];

    float depth = dvals[((size_t)(b * Dc + d)) * HWc + p];
    float fx = (float)w, fy = (float)h;

    float sv[4];
    #pragma unroll
    for (int v = 0; v < 4; ++v) {
        const float* rt = rtS + v * 12;
        float px = (rt[0] * fx + rt[1] * fy + rt[2]) * depth + rt[9];
        float py = (rt[3] * fx + rt[4] * fy + rt[5]) * depth + rt[10];
        float pz = (rt[6] * fx + rt[7] * fy + rt[8]) * depth + rt[11];
        float xs = __fdividef(px, pz);
        float ys = __fdividef(py, pz);
        float fx0 = floorf(xs), fy0 = floorf(ys);
        float wx = xs - fx0, wy = ys - fy0;

        const float* featv = ws + WS_FEATT + ((size_t)((v + 1) * Bc + b)) * HWc * Cc;
        float acc = 0.f;
        #pragma unroll
        for (int ty = 0; ty < 2; ++ty) {
            #pragma unroll
            for (int tx = 0; tx < 2; ++tx) {
                float fxt = fx0 + (float)tx;
                float fyt = fy0 + (float)ty;
                bool valid = (fxt >= 0.f) && (fxt <= (float)(Wc - 1)) &&
                             (fyt >= 0.f) && (fyt <= (float)(Hc - 1));
                float wt = (tx ? wx : 1.f - wx) * (ty ? wy : 1.f - wy);
                if (valid) {
                    int ix = (int)fxt, iy = (int)fyt;
                    const float4* fp = (const float4*)(featv + ((size_t)iy * Wc + ix) * Cc);
                    float dot = 0.f;
                    #pragma unroll
                    for (int i = 0; i < 8; ++i) {
                        float4 fv = fp[i];
                        dot += fv.x * rf[i].x + fv.y * rf[i].y + fv.z * rf[i].z + fv.w * rf[i].w;
                    }
                    acc += wt * dot;
                }
            }
        }
        sv[v] = acc * (1.f / (float)Cc);
    }

    float h1[16][4];
    #pragma unroll
    for (int i = 0; i < 16; ++i) {
        float a = mlpS[i], bb = mlpS[16 + i];
        #pragma unroll
        for (int v = 0; v < 4; ++v) h1[i][v] = fmaxf(a * sv[v] + bb, 0.f);
    }
    float bias2 = mlpS[176];
    float y[4] = {bias2, bias2, bias2, bias2};
    const float4* w1v = (const float4*)(mlpS + 32);
    #pragma unroll
    for (int j = 0; j < 8; ++j) {
        float a0 = mlpS[160 + j];
        float acc[4] = {a0, a0, a0, a0};
        #pragma unroll
        for (int k = 0; k < 4; ++k) {
            float4 wq = w1v[j * 4 + k];
            #pragma unroll
            for (int v = 0; v < 4; ++v) {
                acc[v] += wq.x * h1[4*k+0][v] + wq.y * h1[4*k+1][v]
                        + wq.z * h1[4*k+2][v] + wq.w * h1[4*k+3][v];
            }
        }
        float w2j = mlpS[168 + j];
        #pragma unroll
        for (int v = 0; v < 4; ++v) y[v] += w2j * fmaxf(acc[v], 0.f);
    }

    float vw[4];
    #pragma unroll
    for (int v = 0; v < 4; ++v) {
        float m = __fdividef(1.f, 1.f + __expf(-y[v]));
        #pragma unroll
        for (int off = 16; off; off >>= 1) m = fmaxf(m, __shfl_xor(m, off));
        vw[v] = m;
    }

    float wsum = 1e-5f + vw[0] + vw[1] + vw[2] + vw[3];
    float vol = sv[0] * vw[0] + sv[1] * vw[1] + sv[2] * vw[2] + sv[3] * vw[3];
    ws[WS_SIM + ((size_t)(b * Dc + d)) * HWc + p] = __fdividef(vol, wsum);

    if (d < 4)
        out[OUT_VW + ((size_t)b * 4 + d) * HWc + p] = vw[d];
}

// ---------- SHARED TAIL ----------
// fused 27-tap conv + softmax/argmax. Block = 32 px x 8 d-quads; pre kept in regs,
// softmax via padded-LDS partial reduce across the 8 quads of each pixel.
__global__ __launch_bounds__(256) void convsm_kernel(const float* __restrict__ regb,
                                                     const float* __restrict__ dvals,
                                                     const float* __restrict__ ws,
                                                     float* __restrict__ out) {
    __shared__ float pmaxS[32][9];
    __shared__ int   pidxS[32][9];
    __shared__ float psumS[32][9];

    int tid = threadIdx.x;
    int px = tid & 31, q = tid >> 5;        // q = d-quad 0..7
    int p = blockIdx.x * 32 + px;
    int b = blockIdx.y;
    int h = p / Wc, w = p % Wc;

    float kw[27];
    #pragma unroll
    for (int i = 0; i < 27; ++i) kw[i] = ws[WS_KW + i];

    const float* simb = ws + WS_SIM + (size_t)b * Dc * HWc;
    float acc[4] = {0.f, 0.f, 0.f, 0.f};
    #pragma unroll
    for (int e = -1; e <= 4; ++e) {
        int dd = q * 4 + e;
        if (dd < 0 || dd >= Dc) continue;
        float val[3][3];
        #pragma unroll
        for (int i = 0; i < 3; ++i) {
            int hh = h + i - 1;
            #pragma unroll
            for (int j = 0; j < 3; ++j) {
                int wwp = w + j - 1;
                bool ok = ((unsigned)hh < (unsigned)Hc) && ((unsigned)wwp < (unsigned)Wc);
                val[i][j] = ok ? simb[(size_t)dd * HWc + hh * Wc + wwp] : 0.f;
            }
        }
        #pragma unroll
        for (int kd = 0; kd < 3; ++kd) {
            int tgt = e - kd + 1;
            if (tgt < 0 || tgt > 3) continue;
            float hs = 0.f;
            #pragma unroll
            for (int i = 0; i < 3; ++i)
                #pragma unroll
                for (int j = 0; j < 3; ++j)
                    hs += kw[kd * 9 + i * 3 + j] * val[i][j];
            acc[tgt] += hs;
        }
    }
    float bb = regb[0];
    float pr[4];
    #pragma unroll
    for (int r = 0; r < 4; ++r) pr[r] = acc[r] + bb;

    // partial max/argmax (first occurrence)
    float m = pr[0]; int am = q * 4;
    #pragma unroll
    for (int r = 1; r < 4; ++r) if (pr[r] > m) { m = pr[r]; am = q * 4 + r; }
    pmaxS[px][q] = m; pidxS[px][q] = am;
    __syncthreads();

    float M = -1e30f; int AM = 0;
    #pragma unroll
    for (int k = 0; k < 8; ++k) {
        float om = pmaxS[px][k];
        if (om > M) { M = om; AM = pidxS[px][k]; }
    }
    float e0 = __expf(pr[0] - M), e1 = __expf(pr[1] - M);
    float e2 = __expf(pr[2] - M), e3 = __expf(pr[3] - M);
    psumS[px][q] = (e0 + e1) + (e2 + e3);
    __syncthreads();

    float sum = 0.f;
    #pragma unroll
    for (int k = 0; k < 8; ++k) sum += psumS[px][k];
    float inv = __fdividef(1.f, sum);

    #pragma unroll
    for (int r = 0; r < 4; ++r)
        out[OUT_PROB + ((size_t)(b * Dc + q * 4 + r)) * HWc + p] =
            ((r == 0) ? e0 : (r == 1) ? e1 : (r == 2) ? e2 : e3) * inv;
    if (q == 0) {
        out[OUT_DEPTH + (size_t)b * HWc + p] = dvals[((size_t)(b * Dc + AM)) * HWc + p];
        out[OUT_CONF + (size_t)b * HWc + p] = inv;
    }
}

extern "C" void kernel_launch(void* const* d_in, const int* in_sizes, int n_in,
                              void* d_out, int out_size, void* d_ws, size_t ws_size,
                              hipStream_t stream) {
    const float* features = (const float*)d_in[0];   // (V,B,C,H,W)
    const float* pm       = (const float*)d_in[1];   // (B,V,2,4,4)
    const float* dvals    = (const float*)d_in[2];   // (B,D,H,W)
    const float* pw_w0    = (const float*)d_in[3];
    const float* pw_b0    = (const float*)d_in[4];
    const float* pw_w1    = (const float*)d_in[5];
    const float* pw_b1    = (const float*)d_in[6];
    const float* pw_w2    = (const float*)d_in[7];
    const float* pw_b2    = (const float*)d_in[8];
    const float* reg_w    = (const float*)d_in[9];
    const float* reg_b    = (const float*)d_in[10];
    float* out = (float*)d_out;
    float* ws  = (float*)d_ws;

    prep_kernel<<<1, 64, 0, stream>>>(pm, reg_w, dvals, ws);
    pwl_prep_kernel<<<1, 256, 0, stream>>>(pw_w0, pw_b0, pw_w1, pw_b1, pw_w2, pw_b2, ws);
    check_unif_kernel<<<(Bc * Dc * HWc) / 256, 256, 0, stream>>>(dvals, ws);
    // fallback path (early-exits when fast path valid)
    transpose_kernel<<<dim3(Vc * Bc, HWc / 32), 256, 0, stream>>>(features, ws);
    // fast path
    mapA_kernel<<<dim3((Wc / 32) * (Hc / 8), 8), 256, 0, stream>>>(features, ws);
    fb_main_kernel<<<Bc * HWc / 8, 256, 0, stream>>>(dvals, pw_w0, pw_b0, pw_w1, pw_b1,
                                                     pw_w2, pw_b2, ws, out);
    combine_kernel<<<Bc * HWc / 64, 256, 0, stream>>>(ws, out);
    // shared tail (both paths)
    convsm_kernel<<<dim3(HWc / 32, Bc), 256, 0, stream>>>(reg_b, dvals, ws, out);
}

// Round 9
// 79.010 us; speedup vs baseline: 3.0425x; 1.2646x over previous
//
#include <hip/hip_runtime.h>
#include <math.h>

#define Bc 2
#define Vc 5
#define Cc 32
#define Dc 32
#define Hc 128
#define Wc 160
#define HWc (Hc*Wc)
#define NSLOT 44
#define TILE_CAP 1024

// ---- workspace layout (in floats; _I suffixes are int-indexed via (int*)ws) ----
#define WS_RT     0                       // 8 * 12 floats (rot 9 + trans 3)
#define WS_KW     96                      // 27 collapsed conv taps
#define FLAG_I    128                     // int[2]: [128] translation-ok, [129] dvals-uniform
#define NS_I      136                     // int[8]: slots used per (b,v)
#define SHIFT_I   144                     // 8 * NSLOT * 2 ints (dx,dy), padded with slot0
#define BBOX_I    856                     // 8 bv * 4 ints: dxmin, dymin, dw, dh
#define WS_TAPID  912                     // 8 bv * 32 d * 8 (4 int ids, wx, wy, pad2)
#define WS_PWL    2960                    // [0] int K; +8: knots[256]; +264: alpha[161]; +425: beta[161]
#define WS_M      3584                    // fast: 8 * NSLOT * HW maps | fallback: FEATT overlay
#define WS_FEATT  WS_M
#define WS_SIM    (WS_M + 8*NSLOT*HWc)    // B * D * HW, d-major

// ---- output layout (in floats) ----
#define OUT_DEPTH 0
#define OUT_CONF  (Bc*HWc)
#define OUT_PROB  (2*Bc*HWc)
#define OUT_VW    (2*Bc*HWc + Bc*Dc*HWc)

// k0: block 0 = prep (parallelized); block 1 = PWL table build
__global__ __launch_bounds__(256) void setup_kernel(
        const float* __restrict__ pm, const float* __restrict__ reg_w,
        const float* __restrict__ dvals,
        const float* __restrict__ w0, const float* __restrict__ b0,
        const float* __restrict__ w1, const float* __restrict__ b1,
        const float* __restrict__ w2, const float* __restrict__ b2,
        float* __restrict__ ws) {
    int t = threadIdx.x;
    int* wsi = (int*)ws;

    if (blockIdx.x == 0) {
        // ---------------- prep ----------------
        __shared__ float rtL[8][12];
        __shared__ int okL[8];
        __shared__ int ixL[8][32], iyL[8][32];
        __shared__ float wxL[8][32], wyL[8][32];
        __shared__ int idL[8][32][4];
        __shared__ int shiftL[8][NSLOT][2];

        // phase 1: matrices (8 threads)
        if (t < Bc * (Vc - 1)) {
            int b = t / (Vc - 1);
            int v = t % (Vc - 1) + 1;
            float Pv[16], P0[16];
            for (int which = 0; which < 2; ++which) {
                int vv = which ? 0 : v;
                const float* E = pm + ((b * Vc + vv) * 2 + 0) * 16;
                const float* K = pm + ((b * Vc + vv) * 2 + 1) * 16;
                float* P = which ? P0 : Pv;
                for (int i = 0; i < 3; ++i)
                    for (int j = 0; j < 4; ++j) {
                        float s = 0.f;
                        for (int k = 0; k < 3; ++k) s += K[i*4+k] * E[k*4+j];
                        P[i*4+j] = s;
                    }
                for (int j = 0; j < 4; ++j) P[12+j] = E[12+j];
            }
            float A[16], I[16];
            for (int i = 0; i < 16; ++i) { A[i] = P0[i]; I[i] = (i % 5 == 0) ? 1.f : 0.f; }
            for (int col = 0; col < 4; ++col) {
                int piv = col; float best = fabsf(A[col*4+col]);
                for (int r = col+1; r < 4; ++r) { float av = fabsf(A[r*4+col]); if (av > best) { best = av; piv = r; } }
                if (piv != col)
                    for (int j = 0; j < 4; ++j) {
                        float tmp = A[col*4+j]; A[col*4+j] = A[piv*4+j]; A[piv*4+j] = tmp;
                        tmp = I[col*4+j]; I[col*4+j] = I[piv*4+j]; I[piv*4+j] = tmp;
                    }
                float inv = 1.f / A[col*4+col];
                for (int j = 0; j < 4; ++j) { A[col*4+j] *= inv; I[col*4+j] *= inv; }
                for (int r = 0; r < 4; ++r) if (r != col) {
                    float f = A[r*4+col];
                    for (int j = 0; j < 4; ++j) { A[r*4+j] -= f * A[col*4+j]; I[r*4+j] -= f * I[col*4+j]; }
                }
            }
            float M[16];
            for (int i = 0; i < 4; ++i)
                for (int j = 0; j < 4; ++j) {
                    float s = 0.f;
                    for (int k = 0; k < 4; ++k) s += Pv[i*4+k] * I[k*4+j];
                    M[i*4+j] = s;
                }
            for (int i = 0; i < 3; ++i)
                for (int j = 0; j < 3; ++j) rtL[t][i*3+j] = M[i*4+j];
            rtL[t][9] = M[3]; rtL[t][10] = M[7]; rtL[t][11] = M[11];
            float* rt = ws + WS_RT + t * 12;
            for (int i = 0; i < 12; ++i) rt[i] = rtL[t][i];

            float t2v = M[11];
            okL[t] = (fabsf(M[0]-1.f) < 3e-5f && fabsf(M[1]) < 3e-5f && fabsf(M[2]) < 3e-5f &&
                      fabsf(M[4]) < 3e-5f && fabsf(M[5]-1.f) < 3e-5f && fabsf(M[6]) < 3e-5f &&
                      fabsf(M[8]) < 1e-6f && fabsf(M[9]) < 1e-6f && fabsf(M[10]-1.f) < 1e-6f &&
                      fabsf(t2v) < 1e-6f) ? 1 : 0;
        }
        // conv kernel collapse (threads 32..58, concurrent with matrix phase)
        if (t >= 32 && t < 32 + 27) {
            int k = t - 32;
            float s = 0.f;
            for (int c = 0; c < Cc; ++c) s += reg_w[c * 27 + k];
            ws[WS_KW + k] = s;
        }
        __syncthreads();

        // phase 2: parallel geometry, thread = pair*32 + d
        {
            int pr = t >> 5, d = t & 31;
            int b = pr >> 2;
            float dv = dvals[(size_t)(b * Dc + d) * HWc];
            float t0 = rtL[pr][9], t1 = rtL[pr][10];
            float sx = t0 / dv, sy = t1 / dv;
            float fx0 = floorf(sx), fy0 = floorf(sy);
            ixL[pr][d] = (int)fx0; iyL[pr][d] = (int)fy0;
            wxL[pr][d] = sx - fx0; wyL[pr][d] = sy - fy0;
            idL[pr][d][0] = 0; idL[pr][d][1] = 0; idL[pr][d][2] = 0; idL[pr][d][3] = 0;
        }
        __syncthreads();

        // phase 3: serial per-pair dedupe (LDS-only, 8 threads)
        if (t < 8) {
            bool ok = okL[t] != 0;
            int n = 0;
            if (ok) {
                int pid0 = 0, pid1 = 0, pid2 = 0, pid3 = 0, pix = 0, piy = 0;
                for (int d = 0; d < Dc; ++d) {
                    int ix = ixL[t][d], iy = iyL[t][d];
                    int dxi = ix - pix, dyi = iy - piy;
                    bool reuse = (d > 0) && dxi >= -1 && dxi <= 1 && dyi >= -1 && dyi <= 1;
                    int id0, id1, id2, id3;
                    #define GETPREV(tx2, ty2) ((ty2)==0 ? ((tx2)==0 ? pid0 : pid1) : ((tx2)==0 ? pid2 : pid3))
                    #define DOTAP(idv, tx, ty) { \
                        int tx2 = (tx) + dxi, ty2 = (ty) + dyi; \
                        if (reuse && tx2 >= 0 && tx2 <= 1 && ty2 >= 0 && ty2 <= 1) idv = GETPREV(tx2, ty2); \
                        else { if (n < NSLOT) { shiftL[t][n][0] = ix + (tx); shiftL[t][n][1] = iy + (ty); } \
                               idv = n++; } }
                    DOTAP(id0, 0, 0)
                    DOTAP(id1, 1, 0)
                    DOTAP(id2, 0, 1)
                    DOTAP(id3, 1, 1)
                    #undef DOTAP
                    #undef GETPREV
                    idL[t][d][0] = id0; idL[t][d][1] = id1;
                    idL[t][d][2] = id2; idL[t][d][3] = id3;
                    pid0 = id0; pid1 = id1; pid2 = id2; pid3 = id3; pix = ix; piy = iy;
                }
                if (n > NSLOT) ok = false;
            }
            if (ok) {
                int sx0 = shiftL[t][0][0], sy0 = shiftL[t][0][1];
                for (int s = n; s < NSLOT; ++s) { shiftL[t][s][0] = sx0; shiftL[t][s][1] = sy0; }
                int dxmin = 1 << 28, dxmax = -(1 << 28), dymin = 1 << 28, dymax = -(1 << 28);
                for (int s = 0; s < n; ++s) {
                    int dx = shiftL[t][s][0], dy = shiftL[t][s][1];
                    dxmin = min(dxmin, dx); dxmax = max(dxmax, dx);
                    dymin = min(dymin, dy); dymax = max(dymax, dy);
                }
                int dw = 32 + (dxmax - dxmin);
                int dh = 8 + (dymax - dymin);
                if (dw * dh > TILE_CAP) ok = false;
                wsi[BBOX_I + t*4 + 0] = dxmin;
                wsi[BBOX_I + t*4 + 1] = dymin;
                wsi[BBOX_I + t*4 + 2] = dw;
                wsi[BBOX_I + t*4 + 3] = dh;
            }
            okL[t] = ok ? 1 : 0;
            wsi[NS_I + t] = ok ? n : 0;
        }
        __syncthreads();

        // phase 4: parallel writeout
        {
            int pr = t >> 5, d = t & 31;
            int base = WS_TAPID + (pr * Dc + d) * 8;
            wsi[base+0] = idL[pr][d][0]; wsi[base+1] = idL[pr][d][1];
            wsi[base+2] = idL[pr][d][2]; wsi[base+3] = idL[pr][d][3];
            ws[base+4] = wxL[pr][d]; ws[base+5] = wyL[pr][d];
            ws[base+6] = 0.f; ws[base+7] = 0.f;
        }
        for (int i = t; i < 8 * NSLOT * 2; i += 256) {
            int pr = i / (NSLOT * 2), r = i % (NSLOT * 2);
            wsi[SHIFT_I + i] = shiftL[pr][r >> 1][r & 1];
        }
        if (t == 0) {
            int f = 1;
            for (int i = 0; i < 8; ++i) f &= okL[i];
            wsi[FLAG_I] = f;
            wsi[FLAG_I + 1] = 1;
        }
    } else {
        // ---------------- PWL table build ----------------
        __shared__ float W0[16], B0[16], W1[128], B1[8], W2[8], B2s;
        __shared__ float rawK[160], t0S[16], sortedS[160];
        __shared__ int nrawS;
        if (t < 16) { W0[t] = w0[t]; B0[t] = b0[t]; }
        if (t < 128) W1[t] = w1[t];
        if (t < 8) { B1[t] = b1[t]; W2[t] = w2[t]; }
        if (t == 0) { B2s = b2[0]; nrawS = 0; }
        __syncthreads();
        if (t < 16 && W0[t] != 0.f) {
            int i = atomicAdd(&nrawS, 1);
            rawK[i] = -B0[t] / W0[t];
        }
        __syncthreads();
        int n0 = nrawS;
        if (t < n0) {
            float v = rawK[t]; int r = 0;
            for (int k = 0; k < n0; ++k) { float o = rawK[k]; r += (o < v) || (o == v && k < t); }
            t0S[r] = v;
        }
        __syncthreads();
        if (t < n0) rawK[t] = t0S[t];
        int nItems = 8 * (n0 + 1);
        if (t < nItems) {
            int j = t / (n0 + 1), m = t % (n0 + 1);
            float se;
            if (n0 == 0) se = 0.f;
            else if (m == 0) se = t0S[0] - 1.f;
            else if (m == n0) se = t0S[n0 - 1] + 1.f;
            else se = 0.5f * (t0S[m - 1] + t0S[m]);
            float aval = B1[j], aslp = 0.f;
            for (int i = 0; i < 16; ++i) {
                float pre = W0[i] * se + B0[i];
                if (pre > 0.f) { aval += W1[j * 16 + i] * pre; aslp += W1[j * 16 + i] * W0[i]; }
            }
            if (aslp != 0.f) {
                float sstar = se - aval / aslp;
                float lo = (m == 0) ? -3e38f : t0S[m - 1];
                float hi = (m == n0) ? 3e38f : t0S[m];
                if (sstar > lo && sstar < hi) { int i2 = atomicAdd(&nrawS, 1); rawK[i2] = sstar; }
            }
        }
        __syncthreads();
        int K = nrawS; if (K > 160) K = 160;
        if (t < K) {
            float v = rawK[t]; int r = 0;
            for (int k = 0; k < K; ++k) { float o = rawK[k]; r += (o < v) || (o == v && k < t); }
            sortedS[r] = v;
        }
        __syncthreads();
        ws[WS_PWL + 8 + t] = (t < K) ? sortedS[t] : 1e30f;
        if (t <= K) {
            float se;
            if (K == 0) se = 0.f;
            else if (t == 0) se = sortedS[0] - 1.f;
            else if (t == K) se = sortedS[K - 1] + 1.f;
            else se = 0.5f * (sortedS[t - 1] + sortedS[t]);
            float y = B2s, slp = 0.f;
            for (int j = 0; j < 8; ++j) {
                float aval = B1[j], aslp = 0.f;
                for (int i = 0; i < 16; ++i) {
                    float pre = W0[i] * se + B0[i];
                    if (pre > 0.f) { aval += W1[j * 16 + i] * pre; aslp += W1[j * 16 + i] * W0[i]; }
                }
                if (aval > 0.f) { y += W2[j] * aval; slp += W2[j] * aslp; }
            }
            ws[WS_PWL + 264 + t] = slp;
            ws[WS_PWL + 425 + t] = y - slp * se;
        }
        if (t == 0) ((int*)ws)[WS_PWL] = K;
    }
}

// k0b: verify depth_values uniform over (h,w); clear flag on mismatch
__global__ void check_unif_kernel(const float* __restrict__ dvals, float* __restrict__ ws) {
    int idx = blockIdx.x * 256 + threadIdx.x;
    int plane = idx / HWc;
    float v = dvals[idx];
    if (v != dvals[(size_t)plane * HWc]) ((int*)ws)[FLAG_I + 1] = 0;
}

// ---------- FAST PATH ----------
// kA: LDS-tiled correlation. Block = 32x8 px tile of one bv; 8 channel-groups of 4
// staged as float4 dilated tiles in LDS; 44 branch-free accumulators in VGPRs.
__global__ __launch_bounds__(256) void mapA_kernel(const float* __restrict__ feat,
                                                   float* __restrict__ ws) {
    const int* wsi = (const int*)ws;
    if (!(wsi[FLAG_I] & wsi[FLAG_I + 1])) return;
    __shared__ float4 tile[TILE_CAP];
    __shared__ int shiftS[NSLOT * 2];
    __shared__ int metaS[4];

    int bv = blockIdx.y;
    int tid = threadIdx.x;
    if (tid < NSLOT * 2) shiftS[tid] = wsi[SHIFT_I + bv * NSLOT * 2 + tid];
    if (tid >= 96 && tid < 100) metaS[tid - 96] = wsi[BBOX_I + bv * 4 + (tid - 96)];
    __syncthreads();

    int ns = wsi[NS_I + bv];
    int dxmin = metaS[0], dymin = metaS[1], dw = metaS[2], dh = metaS[3];
    int ntile = dw * dh;

    int bx = blockIdx.x % (Wc / 32), by = blockIdx.x / (Wc / 32);
    int tx0 = bx * 32, ty0 = by * 8;
    int lx = tid & 31, ly = tid >> 5;
    int p = (ty0 + ly) * Wc + tx0 + lx;

    int b = bv >> 2, vm1 = bv & 3;
    const float* refp = feat + (size_t)b * Cc * HWc + p;
    const float* srcb = feat + (size_t)((vm1 + 1) * Bc + b) * Cc * HWc;

    int soff[NSLOT];
    #pragma unroll
    for (int s = 0; s < NSLOT; ++s)
        soff[s] = (shiftS[2 * s + 1] - dymin) * dw + (shiftS[2 * s] - dxmin);
    int loff = ly * dw + lx;

    float acc[NSLOT];
    #pragma unroll
    for (int s = 0; s < NSLOT; ++s) acc[s] = 0.f;

    for (int g = 0; g < 8; ++g) {
        const float* rp = refp + (size_t)(4 * g) * HWc;
        float r0 = rp[0];
        float r1 = rp[(size_t)HWc];
        float r2 = rp[(size_t)2 * HWc];
        float r3 = rp[(size_t)3 * HWc];
        __syncthreads();
        for (int e = tid; e < ntile; e += 256) {
            int r = e / dw, cc = e - r * dw;
            int gx = tx0 + dxmin + cc, gy = ty0 + dymin + r;
            float4 tv = {0.f, 0.f, 0.f, 0.f};
            if ((unsigned)gx < (unsigned)Wc && (unsigned)gy < (unsigned)Hc) {
                const float* sp = srcb + (size_t)(4 * g) * HWc + gy * Wc + gx;
                tv.x = sp[0];
                tv.y = sp[(size_t)HWc];
                tv.z = sp[(size_t)2 * HWc];
                tv.w = sp[(size_t)3 * HWc];
            }
            tile[e] = tv;
        }
        __syncthreads();
        #pragma unroll
        for (int s = 0; s < NSLOT; ++s) {
            float4 tv = tile[soff[s] + loff];
            acc[s] += r0 * tv.x + r1 * tv.y + r2 * tv.z + r3 * tv.w;
        }
    }

    float* Mout = ws + WS_M + (size_t)bv * NSLOT * HWc + p;
    #pragma unroll
    for (int s = 0; s < NSLOT; ++s)
        if (s < ns) Mout[(size_t)s * HWc] = acc[s] * (1.f / 32.f);
}

// kB: fused view-weight + similarity. Block = 64 px x 4 d-octs.
__global__ __launch_bounds__(256) void combine_kernel(float* __restrict__ ws,
                                                      float* __restrict__ out) {
    const int* wsi = (const int*)ws;
    if (!(wsi[FLAG_I] & wsi[FLAG_I + 1])) return;
    __shared__ float knotS[256];
    __shared__ float alphaS[161], betaS[161];
    __shared__ float tapS[4 * Dc * 8];
    __shared__ float redS[4][4][64];

    int tid = threadIdx.x;
    int px = tid & 63, oct = tid >> 6;
    int pg = blockIdx.x * 64 + px;
    int b = pg / HWc, p = pg % HWc;

    knotS[tid] = ws[WS_PWL + 8 + tid];
    if (tid < 161) { alphaS[tid] = ws[WS_PWL + 264 + tid]; betaS[tid] = ws[WS_PWL + 425 + tid]; }
    #pragma unroll
    for (int k = 0; k < 4; ++k)
        tapS[tid + k * 256] = ws[WS_TAPID + b * (4 * Dc * 8) + tid + k * 256];
    __syncthreads();

    float vm[4] = {-1e30f, -1e30f, -1e30f, -1e30f};
    for (int dl = 0; dl < 8; ++dl) {
        int d = oct * 8 + dl;
        #pragma unroll
        for (int v = 0; v < 4; ++v) {
            const float* rec = tapS + ((v * Dc + d) << 3);
            int i00 = __float_as_int(rec[0]);
            int i10 = __float_as_int(rec[1]);
            int i01 = __float_as_int(rec[2]);
            int i11 = __float_as_int(rec[3]);
            float wx = rec[4], wy = rec[5];
            const float* Mb = ws + WS_M + ((size_t)(b * 4 + v)) * NSLOT * HWc + p;
            float m00 = Mb[(size_t)i00 * HWc];
            float m10 = Mb[(size_t)i10 * HWc];
            float m01 = Mb[(size_t)i01 * HWc];
            float m11 = Mb[(size_t)i11 * HWc];
            float top = m00 + wx * (m10 - m00);
            float bot = m01 + wx * (m11 - m01);
            float s = top + wy * (bot - top);
            int seg = 0;
            #pragma unroll
            for (int st = 128; st; st >>= 1) {
                int c = seg + st;
                seg = (s >= knotS[c - 1]) ? c : seg;
            }
            float y = fmaf(alphaS[seg], s, betaS[seg]);
            vm[v] = fmaxf(vm[v], y);
        }
    }
    #pragma unroll
    for (int v = 0; v < 4; ++v) redS[oct][v][px] = vm[v];
    __syncthreads();

    float vw[4];
    float wsum = 1e-5f;
    #pragma unroll
    for (int v = 0; v < 4; ++v) {
        float m = fmaxf(fmaxf(redS[0][v][px], redS[1][v][px]),
                        fmaxf(redS[2][v][px], redS[3][v][px]));
        float sig = __fdividef(1.f, 1.f + __expf(-m));
        vw[v] = sig;
        wsum += sig;
    }
    float invw = __fdividef(1.f, wsum);

    for (int dl = 0; dl < 8; ++dl) {
        int d = oct * 8 + dl;
        float vol = 0.f;
        #pragma unroll
        for (int v = 0; v < 4; ++v) {
            const float* rec = tapS + ((v * Dc + d) << 3);
            int i00 = __float_as_int(rec[0]);
            int i10 = __float_as_int(rec[1]);
            int i01 = __float_as_int(rec[2]);
            int i11 = __float_as_int(rec[3]);
            float wx = rec[4], wy = rec[5];
            const float* Mb = ws + WS_M + ((size_t)(b * 4 + v)) * NSLOT * HWc + p;
            float m00 = Mb[(size_t)i00 * HWc];
            float m10 = Mb[(size_t)i10 * HWc];
            float m01 = Mb[(size_t)i01 * HWc];
            float m11 = Mb[(size_t)i11 * HWc];
            float top = m00 + wx * (m10 - m00);
            float bot = m01 + wx * (m11 - m01);
            vol += (top + wy * (bot - top)) * vw[v];
        }
        ws[WS_SIM + ((size_t)(b * Dc + d)) * HWc + p] = vol * invw;
    }
    if (oct == 0) {
        #pragma unroll
        for (int v = 0; v < 4; ++v)
            out[OUT_VW + ((size_t)(b * 4 + v)) * HWc + p] = vw[v];
    }
}

// ---------- FALLBACK PATH (generic; gated off when fast path valid; grid-stride) ----------
__global__ void transpose_kernel(const float* __restrict__ feat, float* __restrict__ ws) {
    const int* wsi = (const int*)ws;
    if (wsi[FLAG_I] & wsi[FLAG_I + 1]) return;
    __shared__ float tile[32][33];
    int tid = threadIdx.x;
    int total = Vc * Bc * (HWc / 32);
    for (int it = blockIdx.x; it < total; it += gridDim.x) {
        int slab = it / (HWc / 32);
        int pbase = (it % (HWc / 32)) * 32;
        const float* src = feat + (size_t)slab * Cc * HWc;
        float* dst = ws + WS_FEATT + (size_t)slab * HWc * Cc;
        __syncthreads();
        int cc = tid >> 5, pp = tid & 31;
        #pragma unroll
        for (int i = 0; i < 4; ++i) {
            int c = cc + 8 * i;
            tile[c][pp] = src[(size_t)c * HWc + pbase + pp];
        }
        __syncthreads();
        int c2 = tid & 31, p2 = tid >> 5;
        #pragma unroll
        for (int i = 0; i < 4; ++i) {
            int pq = p2 + 8 * i;
            dst[((size_t)(pbase + pq)) * 32 + c2] = tile[c2][pq];
        }
    }
}

__global__ __launch_bounds__(256) void fb_main_kernel(
        const float* __restrict__ dvals,
        const float* __restrict__ w0, const float* __restrict__ b0,
        const float* __restrict__ w1, const float* __restrict__ b1,
        const float* __restrict__ w2, const float* __restrict__ b2,
        float* __restrict__ ws, float* __restrict__ out) {
    const int* wsi = (const int*)ws;
    if (wsi[FLAG_I] & wsi[FLAG_I + 1]) return;
    __shared__ float mlpS[177];
    __shared__ float rtS[96];

    int tid = threadIdx.x;
    if (tid < 16) mlpS[tid] = w0[tid];
    else if (tid < 32) mlpS[tid] = b0[tid - 16];
    else if (tid < 160) mlpS[tid] = w1[tid - 32];
    else if (tid < 168) mlpS[tid] = b1[tid - 160];
    else if (tid < 176) mlpS[tid] = w2[tid - 168];
    else if (tid == 176) mlpS[176] = b2[0];
    if (tid >= 160 && tid < 256 && tid - 160 < 96) rtS[tid - 160] = ws[WS_RT + (tid - 160)];
    __syncthreads();

    int d = tid & 31;
    int pgq = tid >> 5;

    for (int bid = blockIdx.x; bid < Bc * HWc / 8; bid += gridDim.x) {
        int b = bid / (HWc / 8);
        int pblk = (bid % (HWc / 8)) * 8;
        int p = pblk + pgq;
        int h = p / Wc, w = p % Wc;

        const float4* refp = (const float4*)(ws + WS_FEATT + ((size_t)b * HWc + p) * Cc);
        float4 rf[8];
        #pragma unroll
        for (int i = 0; i < 8; ++i) rf[i] = refp[i];

        float depth = dvals[((size_t)(b * Dc + d)) * HWc + p];
        float fx = (float)w, fy = (float)h;

        float sv[4];
        #pragma unroll
        for (int v = 0; v < 4; ++v) {
            const float* rt = rtS + (b * 4 + v) * 12;
            float px = (rt[0] * fx + rt[1] * fy + rt[2]) * depth + rt[9];
            float py = (rt[3] * fx + rt[4] * fy + rt[5]) * depth + rt[10];
            float pz = (rt[6] * fx + rt[7] * fy + rt[8]) * depth + rt[11];
            float xs = __fdividef(px, pz);
            float ys = __fdividef(py, pz);
            float fx0 = floorf(xs), fy0 = floorf(ys);
            float wx = xs - fx0, wy = ys - fy0;

            const float* featv = ws + WS_FEATT + ((size_t)((v + 1) * Bc + b)) * HWc * Cc;
            float acc = 0.f;
            #pragma unroll
            for (int ty = 0; ty < 2; ++ty) {
                #pragma unroll
                for (int tx = 0; tx < 2; ++tx) {
                    float fxt = fx0 + (float)tx;
                    float fyt = fy0 + (float)ty;
                    bool valid = (fxt >= 0.f) && (fxt <= (float)(Wc - 1)) &&
                                 (fyt >= 0.f) && (fyt <= (float)(Hc - 1));
                    float wt = (tx ? wx : 1.f - wx) * (ty ? wy : 1.f - wy);
                    if (valid) {
                        int ix = (int)fxt, iy = (int)fyt;
                        const float4* fp = (const float4*)(featv + ((size_t)iy * Wc + ix) * Cc);
                        float dot = 0.f;
                        #pragma unroll
                        for (int i = 0; i < 8; ++i) {
                            float4 fv = fp[i];
                            dot += fv.x * rf[i].x + fv.y * rf[i].y + fv.z * rf[i].z + fv.w * rf[i].w;
                        }
                        acc += wt * dot;
                    }
                }
            }
            sv[v] = acc * (1.f / (float)Cc);
        }

        float h1[16][4];
        #pragma unroll
        for (int i = 0; i < 16; ++i) {
            float a = mlpS[i], bb = mlpS[16 + i];
            #pragma unroll
            for (int v = 0; v < 4; ++v) h1[i][v] = fmaxf(a * sv[v] + bb, 0.f);
        }
        float bias2 = mlpS[176];
        float y[4] = {bias2, bias2, bias2, bias2};
        const float4* w1v = (const float4*)(mlpS + 32);
        #pragma unroll
        for (int j = 0; j < 8; ++j) {
            float a0 = mlpS[160 + j];
            float acc[4] = {a0, a0, a0, a0};
            #pragma unroll
            for (int k = 0; k < 4; ++k) {
                float4 wq = w1v[j * 4 + k];
                #pragma unroll
                for (int v = 0; v < 4; ++v) {
                    acc[v] += wq.x * h1[4*k+0][v] + wq.y * h1[4*k+1][v]
                            + wq.z * h1[4*k+2][v] + wq.w * h1[4*k+3][v];
                }
            }
            float w2j = mlpS[168 + j];
            #pragma unroll
            for (int v = 0; v < 4; ++v) y[v] += w2j * fmaxf(acc[v], 0.f);
        }

        float vw[4];
        #pragma unroll
        for (int v = 0; v < 4; ++v) {
            float m = __fdividef(1.f, 1.f + __expf(-y[v]));
            #pragma unroll
            for (int off = 16; off; off >>= 1) m = fmaxf(m, __shfl_xor(m, off));
            vw[v] = m;
        }

        float wsum = 1e-5f + vw[0] + vw[1] + vw[2] + vw[3];
        float vol = sv[0] * vw[0] + sv[1] * vw[1] + sv[2] * vw[2] + sv[3] * vw[3];
        ws[WS_SIM + ((size_t)(b * Dc + d)) * HWc + p] = __fdividef(vol, wsum);

        if (d < 4)
            out[OUT_VW + ((size_t)b * 4 + d) * HWc + p] = vw[d];
    }
}

// ---------- SHARED TAIL ----------
// fused 27-tap conv + softmax/argmax. Block = 32 px x 8 d-quads.
__global__ __launch_bounds__(256) void convsm_kernel(const float* __restrict__ regb,
                                                     const float* __restrict__ dvals,
                                                     const float* __restrict__ ws,
                                                     float* __restrict__ out) {
    __shared__ float pmaxS[32][9];
    __shared__ int   pidxS[32][9];
    __shared__ float psumS[32][9];

    int tid = threadIdx.x;
    int px = tid & 31, q = tid >> 5;
    int p = blockIdx.x * 32 + px;
    int b = blockIdx.y;
    int h = p / Wc, w = p % Wc;

    float kw[27];
    #pragma unroll
    for (int i = 0; i < 27; ++i) kw[i] = ws[WS_KW + i];

    const float* simb = ws + WS_SIM + (size_t)b * Dc * HWc;
    float acc[4] = {0.f, 0.f, 0.f, 0.f};
    #pragma unroll
    for (int e = -1; e <= 4; ++e) {
        int dd = q * 4 + e;
        if (dd < 0 || dd >= Dc) continue;
        float val[3][3];
        #pragma unroll
        for (int i = 0; i < 3; ++i) {
            int hh = h + i - 1;
            #pragma unroll
            for (int j = 0; j < 3; ++j) {
                int wwp = w + j - 1;
                bool ok = ((unsigned)hh < (unsigned)Hc) && ((unsigned)wwp < (unsigned)Wc);
                val[i][j] = ok ? simb[(size_t)dd * HWc + hh * Wc + wwp] : 0.f;
            }
        }
        #pragma unroll
        for (int kd = 0; kd < 3; ++kd) {
            int tgt = e - kd + 1;
            if (tgt < 0 || tgt > 3) continue;
            float hs = 0.f;
            #pragma unroll
            for (int i = 0; i < 3; ++i)
                #pragma unroll
                for (int j = 0; j < 3; ++j)
                    hs += kw[kd * 9 + i * 3 + j] * val[i][j];
            acc[tgt] += hs;
        }
    }
    float bb = regb[0];
    float pr[4];
    #pragma unroll
    for (int r = 0; r < 4; ++r) pr[r] = acc[r] + bb;

    float m = pr[0]; int am = q * 4;
    #pragma unroll
    for (int r = 1; r < 4; ++r) if (pr[r] > m) { m = pr[r]; am = q * 4 + r; }
    pmaxS[px][q] = m; pidxS[px][q] = am;
    __syncthreads();

    float M = -1e30f; int AM = 0;
    #pragma unroll
    for (int k = 0; k < 8; ++k) {
        float om = pmaxS[px][k];
        if (om > M) { M = om; AM = pidxS[px][k]; }
    }
    float e0 = __expf(pr[0] - M), e1 = __expf(pr[1] - M);
    float e2 = __expf(pr[2] - M), e3 = __expf(pr[3] - M);
    psumS[px][q] = (e0 + e1) + (e2 + e3);
    __syncthreads();

    float sum = 0.f;
    #pragma unroll
    for (int k = 0; k < 8; ++k) sum += psumS[px][k];
    float inv = __fdividef(1.f, sum);

    #pragma unroll
    for (int r = 0; r < 4; ++r)
        out[OUT_PROB + ((size_t)(b * Dc + q * 4 + r)) * HWc + p] =
            ((r == 0) ? e0 : (r == 1) ? e1 : (r == 2) ? e2 : e3) * inv;
    if (q == 0) {
        out[OUT_DEPTH + (size_t)b * HWc + p] = dvals[((size_t)(b * Dc + AM)) * HWc + p];
        out[OUT_CONF + (size_t)b * HWc + p] = inv;
    }
}

extern "C" void kernel_launch(void* const* d_in, const int* in_sizes, int n_in,
                              void* d_out, int out_size, void* d_ws, size_t ws_size,
                              hipStream_t stream) {
    const float* features = (const float*)d_in[0];   // (V,B,C,H,W)
    const float* pm       = (const float*)d_in[1];   // (B,V,2,4,4)
    const float* dvals    = (const float*)d_in[2];   // (B,D,H,W)
    const float* pw_w0    = (const float*)d_in[3];
    const float* pw_b0    = (const float*)d_in[4];
    const float* pw_w1    = (const float*)d_in[5];
    const float* pw_b1    = (const float*)d_in[6];
    const float* pw_w2    = (const float*)d_in[7];
    const float* pw_b2    = (const float*)d_in[8];
    const float* reg_w    = (const float*)d_in[9];
    const float* reg_b    = (const float*)d_in[10];
    float* out = (float*)d_out;
    float* ws  = (float*)d_ws;

    setup_kernel<<<2, 256, 0, stream>>>(pm, reg_w, dvals, pw_w0, pw_b0, pw_w1, pw_b1,
                                        pw_w2, pw_b2, ws);
    check_unif_kernel<<<(Bc * Dc * HWc) / 256, 256, 0, stream>>>(dvals, ws);
    // fallback path (early-exits when fast path valid; grid-stride small grids)
    transpose_kernel<<<320, 256, 0, stream>>>(features, ws);
    // fast path
    mapA_kernel<<<dim3((Wc / 32) * (Hc / 8), 8), 256, 0, stream>>>(features, ws);
    fb_main_kernel<<<320, 256, 0, stream>>>(dvals, pw_w0, pw_b0, pw_w1, pw_b1,
                                            pw_w2, pw_b2, ws, out);
    combine_kernel<<<Bc * HWc / 64, 256, 0, stream>>>(ws, out);
    // shared tail (both paths)
    convsm_kernel<<<dim3(HWc / 32, Bc), 256, 0, stream>>>(reg_b, dvals, ws, out);
}